// Round 2
// baseline (299.391 us; speedup 1.0000x reference)
//
#include <hip/hip_runtime.h>
#include <hip/hip_bf16.h>
#include <stdint.h>

#define BB 2
#define TT 2048
#define CC 1024
#define HH 16
#define DD 64
#define MM (BB*TT)   // 4096 rows

typedef __bf16 bf16x8 __attribute__((ext_vector_type(8)));
typedef float  f32x4  __attribute__((ext_vector_type(4)));
typedef unsigned short u16;
typedef unsigned int   u32;

// float -> bf16 bits, RTNE
__device__ __forceinline__ u16 f2bf(float f) {
  u32 u = __float_as_uint(f);
  return (u16)((u + 0x7fffu + ((u >> 16) & 1u)) >> 16);
}

// async global->LDS, 16B per lane. LDS dest is wave-uniform base (+lane*16 by HW).
__device__ __forceinline__ void gload_lds16(const u16* g, u16* l) {
  auto gp = (const u32 __attribute__((address_space(1)))*)(uintptr_t)g;
  auto lp = (u32 __attribute__((address_space(3)))*)(u32)(uintptr_t)l;
  __builtin_amdgcn_global_load_lds(gp, lp, 16, 0, 0);
}

// ---------------- kernel D: detect whether integer inputs are int32 or int8 --------
__global__ __launch_bounds__(256)
void k_detect(const int* __restrict__ w, int* __restrict__ flag) {
  int bad = 0;
  #pragma unroll
  for (int i = 0; i < 4; ++i) {
    int v = w[threadIdx.x * 4 + i];
    bad |= (v < -128) | (v > 127);
  }
  unsigned long long b = __ballot(bad != 0);
  __shared__ unsigned long long sb[4];
  if ((threadIdx.x & 63) == 0) sb[threadIdx.x >> 6] = b;
  __syncthreads();
  if (threadIdx.x == 0) flag[0] = ((sb[0] | sb[1] | sb[2] | sb[3]) == 0ull) ? 1 : 0;
}

// ---------------- kernel S: sentinel (ws too small -> diagnostic output) ------------
__global__ __launch_bounds__(256)
void k_sentinel(float* __restrict__ out, int n) {
  int i = blockIdx.x * 256 + threadIdx.x;
  if (i < n) out[i] = 9999.0f;
}

// ---------------- kernel 0: convert x fp32->bf16, weights int->bf16 (exact) --------
__global__ __launch_bounds__(256)
void k_convert(const float* __restrict__ x,
               const void* __restrict__ w0, const void* __restrict__ w1,
               const void* __restrict__ w2, const void* __restrict__ w3,
               const int* __restrict__ flag,
               u16* __restrict__ xb, u16* __restrict__ wb) {
  const int idx = blockIdx.x * 256 + threadIdx.x;
  const int NX = MM * CC / 4;          // 1048576 float4 units
  if (idx < NX) {
    float4 v = ((const float4*)x)[idx];
    u32 lo = (u32)f2bf(v.x) | ((u32)f2bf(v.y) << 16);
    u32 hi = (u32)f2bf(v.z) | ((u32)f2bf(v.w) << 16);
    ((uint2*)xb)[idx] = make_uint2(lo, hi);
  } else {
    int u = idx - NX;                  // 0..1048575 ; 262144 4-weight units per matrix
    int mat = u >> 18;
    int j = u & 262143;
    const void* ws = (mat == 0) ? w0 : (mat == 1) ? w1 : (mat == 2) ? w2 : w3;
    u32 lo, hi;
    if (flag[0]) {                     // weights are int32 (harness presents int as int*)
      int4 v = ((const int4*)ws)[j];
      lo = (u32)f2bf((float)v.x) | ((u32)f2bf((float)v.y) << 16);
      hi = (u32)f2bf((float)v.z) | ((u32)f2bf((float)v.w) << 16);
    } else {                           // raw int8 layout
      int32_t v = ((const int32_t*)ws)[j];
      lo = (u32)f2bf((float)(int8_t)(v & 0xff)) |
           ((u32)f2bf((float)(int8_t)((v >> 8) & 0xff)) << 16);
      hi = (u32)f2bf((float)(int8_t)((v >> 16) & 0xff)) |
           ((u32)f2bf((float)(int8_t)(v >> 24)) << 16);
    }
    ((uint2*)wb)[(mat << 18) + j] = make_uint2(lo, hi);
  }
}

// ---------------- shared GEMM core: C[128x128] = A[128xK] * W[128xK]^T --------------
__device__ __forceinline__ void gemm_core(const u16* __restrict__ Ag,
                                          const u16* __restrict__ Wg,
                                          int brow, int bcol,
                                          u16* As, u16* Bs, f32x4 acc[4][4]) {
  const int tid  = threadIdx.x;
  const int w    = tid >> 6;
  const int lane = tid & 63;
  const int q = lane & 15, g = lane >> 4;
  const int wm = w >> 1, wn = w & 1;

  for (int kt = 0; kt < CC / 32; ++kt) {
    #pragma unroll
    for (int i = 0; i < 2; ++i) {
      int Lg  = i * 256 + tid;         // granule id (16B each); [128][32]bf16 = 512 granules
      int row = Lg >> 2, gc = Lg & 3;
      gload_lds16(Ag + (brow + row) * CC + kt * 32 + gc * 8, As + (i * 256 + w * 64) * 8);
      gload_lds16(Wg + (bcol + row) * CC + kt * 32 + gc * 8, Bs + (i * 256 + w * 64) * 8);
    }
    __syncthreads();
    bf16x8 af[4], bff[4];
    #pragma unroll
    for (int a = 0; a < 4; ++a) af[a]  = *(const bf16x8*)&As[(wm * 64 + a * 16 + q) * 32 + g * 8];
    #pragma unroll
    for (int b = 0; b < 4; ++b) bff[b] = *(const bf16x8*)&Bs[(wn * 64 + b * 16 + q) * 32 + g * 8];
    #pragma unroll
    for (int a = 0; a < 4; ++a) {
      #pragma unroll
      for (int b = 0; b < 4; ++b) {
        acc[a][b] = __builtin_amdgcn_mfma_f32_16x16x32_bf16(af[a], bff[b], acc[a][b], 0, 0, 0);
      }
    }
    __syncthreads();
  }
}

// ---------------- kernel 1: QKV projection -> Q,K (B,H,T,D) and V^T (B,H,D,T) ------
__global__ __launch_bounds__(256)
void k_gemm_qkv(const u16* __restrict__ xb, const u16* __restrict__ wb,
                const float* __restrict__ sq, const float* __restrict__ bq,
                const float* __restrict__ sk, const float* __restrict__ bk,
                const float* __restrict__ sv, const float* __restrict__ bv,
                u16* __restrict__ Qo, u16* __restrict__ Ko, u16* __restrict__ Vt) {
  __shared__ u16 As[128 * 32];
  __shared__ u16 Bs[128 * 32];
  const int bid  = blockIdx.x;
  const int brow = (bid & 31) * 128;
  const int ncol = (bid >> 5) * 128;   // 0..3071
  const int mat  = ncol >> 10;
  const int bcol = ncol & 1023;
  const u16* W = wb + (mat << 20);

  f32x4 acc[4][4];
  #pragma unroll
  for (int a = 0; a < 4; ++a)
    #pragma unroll
    for (int b = 0; b < 4; ++b) { f32x4 z = {0.f, 0.f, 0.f, 0.f}; acc[a][b] = z; }

  gemm_core(xb, W, brow, bcol, As, Bs, acc);

  const int tid = threadIdx.x;
  const int w = tid >> 6, lane = tid & 63;
  const int q = lane & 15, g = lane >> 4;
  const int wm = w >> 1, wn = w & 1;
  const float* sarr = (mat == 0) ? sq : (mat == 1) ? sk : sv;
  const float* barr = (mat == 0) ? bq : (mat == 1) ? bk : bv;

  #pragma unroll
  for (int bt = 0; bt < 4; ++bt) {
    const int c = bcol + wn * 64 + bt * 16 + q;   // channel within matrix, 0..1023
    const float sc = sarr[c];
    const float bi = barr[c];
    const int h = c >> 6, d = c & 63;
    #pragma unroll
    for (int a = 0; a < 4; ++a) {
      #pragma unroll
      for (int r = 0; r < 4; ++r) {
        const int m = brow + wm * 64 + a * 16 + 4 * g + r;  // token row 0..4095
        const int b_ = m >> 11, t = m & 2047;
        const u16 val = f2bf(acc[a][bt][r] * sc + bi);
        if (mat == 0)      Qo[(((size_t)(b_ * HH + h) * TT) + t) * DD + d] = val;
        else if (mat == 1) Ko[(((size_t)(b_ * HH + h) * TT) + t) * DD + d] = val;
        else               Vt[((size_t)(b_ * HH + h) * DD + d) * TT + t] = val;  // V^T direct
      }
    }
  }
}

// ---------------- kernel 2: causal flash attention ----------------------------------
// Wave handles 16 q-rows. Swapped QK^T: S^T = K*Q^T so softmax row = lane&15.
// PV: O^T = V^T * P^T (V^T contiguous loads; P^T re-laid out via 1KB wave-local LDS).
__global__ __launch_bounds__(256)
void k_attn(const u16* __restrict__ Q, const u16* __restrict__ K,
            const u16* __restrict__ Vt, u16* __restrict__ Y) {
  __shared__ u16 pbuf[4][16 * 40];   // per-wave P[q][key 0..31], stride 40 (pad)
  const int tid = threadIdx.x;
  const int w = tid >> 6, lane = tid & 63;
  const int q = lane & 15, g = lane >> 4;
  const int bid = blockIdx.x;
  const int bh = bid >> 5;                 // 0..31
  const int ti = (bid & 31) * 4 + w;       // q-tile 0..127
  const int qbase = ti * 16;
  const int qg = qbase + q;
  const u16* Qh = Q  + (size_t)bh * TT * DD;
  const u16* Kh = K  + (size_t)bh * TT * DD;
  const u16* Vh = Vt + (size_t)bh * DD * TT;
  u16* pl = pbuf[w];

  bf16x8 qf0 = *(const bf16x8*)&Qh[(qbase + q) * DD + g * 8];
  bf16x8 qf1 = *(const bf16x8*)&Qh[(qbase + q) * DD + 32 + g * 8];

  f32x4 oacc[4];
  #pragma unroll
  for (int dt = 0; dt < 4; ++dt) { f32x4 z = {0.f, 0.f, 0.f, 0.f}; oacc[dt] = z; }
  float m_run = -__builtin_inff();
  float l_run = 0.f;
  const int nkb = (qbase + 47) >> 5;       // blocks of 32 keys covering 0..qbase+15
  constexpr float SE = 0.125f * 1.44269504088896340736f;  // scale * log2(e)

  for (int kb = 0; kb < nkb; ++kb) {
    const int kbase = kb * 32;
    f32x4 s0 = {0.f, 0.f, 0.f, 0.f}, s1 = {0.f, 0.f, 0.f, 0.f};
    {
      const u16* kr = &Kh[(kbase + q) * DD + g * 8];
      bf16x8 k00 = *(const bf16x8*)(kr);
      bf16x8 k01 = *(const bf16x8*)(kr + 32);
      bf16x8 k10 = *(const bf16x8*)(kr + 16 * DD);
      bf16x8 k11 = *(const bf16x8*)(kr + 16 * DD + 32);
      s0 = __builtin_amdgcn_mfma_f32_16x16x32_bf16(k00, qf0, s0, 0, 0, 0);
      s0 = __builtin_amdgcn_mfma_f32_16x16x32_bf16(k01, qf1, s0, 0, 0, 0);
      s1 = __builtin_amdgcn_mfma_f32_16x16x32_bf16(k10, qf0, s1, 0, 0, 0);
      s1 = __builtin_amdgcn_mfma_f32_16x16x32_bf16(k11, qf1, s1, 0, 0, 0);
    }
    // S^T layout: lane holds col q (= softmax row), rows key = t*16 + 4g + r
    float sv[8];
    #pragma unroll
    for (int r = 0; r < 4; ++r) { sv[r] = s0[r] * SE; sv[4 + r] = s1[r] * SE; }
    if (kbase + 31 > qbase) {   // partial/causal block
      #pragma unroll
      for (int r = 0; r < 4; ++r) {
        if (kbase + 4 * g + r > qg)      sv[r]     = -__builtin_inff();
        if (kbase + 16 + 4 * g + r > qg) sv[4 + r] = -__builtin_inff();
      }
    }
    float pmax = sv[0];
    #pragma unroll
    for (int j = 1; j < 8; ++j) pmax = fmaxf(pmax, sv[j]);
    pmax = fmaxf(pmax, __shfl_xor(pmax, 16));
    pmax = fmaxf(pmax, __shfl_xor(pmax, 32));
    const float m_new = fmaxf(m_run, pmax);
    const float alpha = __builtin_amdgcn_exp2f(m_run - m_new);
    float p[8]; float psum = 0.f;
    #pragma unroll
    for (int j = 0; j < 8; ++j) { p[j] = __builtin_amdgcn_exp2f(sv[j] - m_new); psum += p[j]; }
    l_run = l_run * alpha + psum;
    m_run = m_new;
    #pragma unroll
    for (int dt = 0; dt < 4; ++dt) oacc[dt] *= alpha;

    // wave-local LDS round trip: P^T (D-layout) -> P[q][key] -> b128 B-fragment
    const u32 w0 = (u32)f2bf(p[0]) | ((u32)f2bf(p[1]) << 16);
    const u32 w1 = (u32)f2bf(p[2]) | ((u32)f2bf(p[3]) << 16);
    const u32 w2 = (u32)f2bf(p[4]) | ((u32)f2bf(p[5]) << 16);
    const u32 w3 = (u32)f2bf(p[6]) | ((u32)f2bf(p[7]) << 16);
    *(uint2*)&pl[q * 40 + 4 * g]      = make_uint2(w0, w1);
    *(uint2*)&pl[q * 40 + 16 + 4 * g] = make_uint2(w2, w3);
    asm volatile("s_waitcnt lgkmcnt(0)" ::: "memory");
    __builtin_amdgcn_sched_barrier(0);
    bf16x8 pf = *(const bf16x8*)&pl[q * 40 + 8 * g];
    #pragma unroll
    for (int dt = 0; dt < 4; ++dt) {
      bf16x8 vf = *(const bf16x8*)&Vh[(dt * 16 + q) * TT + kbase + 8 * g];
      oacc[dt] = __builtin_amdgcn_mfma_f32_16x16x32_bf16(vf, pf, oacc[dt], 0, 0, 0);
    }
  }
  float lt = l_run;
  lt += __shfl_xor(lt, 16);
  lt += __shfl_xor(lt, 32);
  const float inv = 1.f / (lt + 1e-8f);
  const int b_ = bh >> 4, h = bh & 15;
  #pragma unroll
  for (int dt = 0; dt < 4; ++dt) {
    u32 lo = (u32)f2bf(oacc[dt][0] * inv) | ((u32)f2bf(oacc[dt][1] * inv) << 16);
    u32 hi = (u32)f2bf(oacc[dt][2] * inv) | ((u32)f2bf(oacc[dt][3] * inv) << 16);
    *(uint2*)&Y[(size_t)(b_ * TT + qg) * CC + h * 64 + dt * 16 + 4 * g] = make_uint2(lo, hi);
  }
}

// ---------------- kernel 3: output projection -> fp32 d_out -------------------------
__global__ __launch_bounds__(256)
void k_gemm_o(const u16* __restrict__ Yb, const u16* __restrict__ Wo,
              const float* __restrict__ so, const float* __restrict__ bo,
              float* __restrict__ out) {
  __shared__ u16 As[128 * 32];
  __shared__ u16 Bs[128 * 32];
  const int bid = blockIdx.x;
  const int brow = (bid & 31) * 128;
  const int bcol = (bid >> 5) * 128;
  f32x4 acc[4][4];
  #pragma unroll
  for (int a = 0; a < 4; ++a)
    #pragma unroll
    for (int b = 0; b < 4; ++b) { f32x4 z = {0.f, 0.f, 0.f, 0.f}; acc[a][b] = z; }

  gemm_core(Yb, Wo, brow, bcol, As, Bs, acc);

  const int tid = threadIdx.x;
  const int w = tid >> 6, lane = tid & 63;
  const int q = lane & 15, g = lane >> 4;
  const int wm = w >> 1, wn = w & 1;
  #pragma unroll
  for (int bt = 0; bt < 4; ++bt) {
    const int c = bcol + wn * 64 + bt * 16 + q;
    const float sc = so[c], bi = bo[c];
    #pragma unroll
    for (int a = 0; a < 4; ++a) {
      const int mbase = brow + wm * 64 + a * 16 + 4 * g;
      #pragma unroll
      for (int r = 0; r < 4; ++r) {
        out[(size_t)(mbase + r) * CC + c] = acc[a][bt][r] * sc + bi;
      }
    }
  }
}

// ---------------- launcher -----------------------------------------------------------
extern "C" void kernel_launch(void* const* d_in, const int* in_sizes, int n_in,
                              void* d_out, int out_size, void* d_ws, size_t ws_size,
                              hipStream_t stream) {
  const float* x  = (const float*)d_in[0];
  const void*  wq = d_in[1];
  const float* sq = (const float*)d_in[2];
  const float* bq = (const float*)d_in[3];
  const void*  wk = d_in[4];
  const float* sk = (const float*)d_in[5];
  const float* bk = (const float*)d_in[6];
  const void*  wv = d_in[7];
  const float* sv = (const float*)d_in[8];
  const float* bv = (const float*)d_in[9];
  const void*  wo = d_in[10];
  const float* so = (const float*)d_in[11];
  const float* bo = (const float*)d_in[12];

  const size_t NEED = (40u << 20) + 4096;
  if (ws_size < NEED) {   // diagnostic: error magnitude ~9999 => scratch too small
    k_sentinel<<<dim3((out_size + 255) / 256), dim3(256), 0, stream>>>((float*)d_out, out_size);
    return;
  }

  char* ws = (char*)d_ws;
  u16* xb = (u16*)(ws);                      // 8 MB  (x bf16; reused as Y later)
  u16* wb = (u16*)(ws + (8u  << 20));        // 8 MB  (4 weight matrices bf16)
  u16* Qb = (u16*)(ws + (16u << 20));        // 8 MB
  u16* Kb = (u16*)(ws + (24u << 20));        // 8 MB
  u16* Vt = (u16*)(ws + (32u << 20));        // 8 MB  (V^T, written directly by QKV GEMM)
  int* flag = (int*)(ws + (40u << 20));      // 4 B
  u16* Yb = xb;                              // x dead after QKV GEMM

  k_detect  <<<dim3(1),    dim3(256), 0, stream>>>((const int*)wq, flag);
  k_convert <<<dim3(8192), dim3(256), 0, stream>>>(x, wq, wk, wv, wo, flag, xb, wb);
  k_gemm_qkv<<<dim3(768),  dim3(256), 0, stream>>>(xb, wb, sq, bq, sk, bk, sv, bv, Qb, Kb, Vt);
  k_attn    <<<dim3(1024), dim3(256), 0, stream>>>(Qb, Kb, Vt, Yb);
  k_gemm_o  <<<dim3(256),  dim3(256), 0, stream>>>(Yb, wb + (3u << 20), so, bo, (float*)d_out);
}

// Round 3
// 148.992 us; speedup vs baseline: 2.0094x; 2.0094x over previous
//
#include <hip/hip_runtime.h>
#include <hip/hip_bf16.h>
#include <stdint.h>

#define BB 2
#define TT 2048
#define CC 1024
#define HH 16
#define DD 64
#define MM (BB*TT)   // 4096 rows

typedef __bf16 bf16x8 __attribute__((ext_vector_type(8)));
typedef float  f32x4  __attribute__((ext_vector_type(4)));
typedef unsigned short u16;
typedef unsigned int   u32;

// float -> bf16 bits, RTNE
__device__ __forceinline__ u16 f2bf(float f) {
  u32 u = __float_as_uint(f);
  return (u16)((u + 0x7fffu + ((u >> 16) & 1u)) >> 16);
}

// async global->LDS, 16B per lane. LDS dest is wave-uniform base (+lane*16 by HW).
__device__ __forceinline__ void gload_lds16(const u16* g, u16* l) {
  auto gp = (const u32 __attribute__((address_space(1)))*)(uintptr_t)g;
  auto lp = (u32 __attribute__((address_space(3)))*)(u32)(uintptr_t)l;
  __builtin_amdgcn_global_load_lds(gp, lp, 16, 0, 0);
}

// ---------------- kernel D: detect whether integer inputs are int32 or int8 --------
__global__ __launch_bounds__(256)
void k_detect(const int* __restrict__ w, int* __restrict__ flag) {
  int bad = 0;
  #pragma unroll
  for (int i = 0; i < 4; ++i) {
    int v = w[threadIdx.x * 4 + i];
    bad |= (v < -128) | (v > 127);
  }
  unsigned long long b = __ballot(bad != 0);
  __shared__ unsigned long long sb[4];
  if ((threadIdx.x & 63) == 0) sb[threadIdx.x >> 6] = b;
  __syncthreads();
  if (threadIdx.x == 0) flag[0] = ((sb[0] | sb[1] | sb[2] | sb[3]) == 0ull) ? 1 : 0;
}

// ---------------- kernel S: sentinel (ws too small -> diagnostic output) ------------
__global__ __launch_bounds__(256)
void k_sentinel(float* __restrict__ out, int n) {
  int i = blockIdx.x * 256 + threadIdx.x;
  if (i < n) out[i] = 9999.0f;
}

// ---------------- kernel 0: convert x fp32->bf16, weights int->bf16 (exact) --------
__global__ __launch_bounds__(256)
void k_convert(const float* __restrict__ x,
               const void* __restrict__ w0, const void* __restrict__ w1,
               const void* __restrict__ w2, const void* __restrict__ w3,
               const int* __restrict__ flag,
               u16* __restrict__ xb, u16* __restrict__ wb) {
  const int idx = blockIdx.x * 256 + threadIdx.x;
  const int NX = MM * CC / 4;          // 1048576 float4 units
  if (idx < NX) {
    float4 v = ((const float4*)x)[idx];
    u32 lo = (u32)f2bf(v.x) | ((u32)f2bf(v.y) << 16);
    u32 hi = (u32)f2bf(v.z) | ((u32)f2bf(v.w) << 16);
    ((uint2*)xb)[idx] = make_uint2(lo, hi);
  } else {
    int u = idx - NX;                  // 0..1048575 ; 262144 4-weight units per matrix
    int mat = u >> 18;
    int j = u & 262143;
    const void* ws = (mat == 0) ? w0 : (mat == 1) ? w1 : (mat == 2) ? w2 : w3;
    u32 lo, hi;
    if (flag[0]) {                     // weights are int32 (harness presents int as int*)
      int4 v = ((const int4*)ws)[j];
      lo = (u32)f2bf((float)v.x) | ((u32)f2bf((float)v.y) << 16);
      hi = (u32)f2bf((float)v.z) | ((u32)f2bf((float)v.w) << 16);
    } else {                           // raw int8 layout
      int32_t v = ((const int32_t*)ws)[j];
      lo = (u32)f2bf((float)(int8_t)(v & 0xff)) |
           ((u32)f2bf((float)(int8_t)((v >> 8) & 0xff)) << 16);
      hi = (u32)f2bf((float)(int8_t)((v >> 16) & 0xff)) |
           ((u32)f2bf((float)(int8_t)(v >> 24)) << 16);
    }
    ((uint2*)wb)[(mat << 18) + j] = make_uint2(lo, hi);
  }
}

// ---------------- shared GEMM core: C[128x128] = A[128xK] * W[128xK]^T --------------
__device__ __forceinline__ void gemm_core(const u16* __restrict__ Ag,
                                          const u16* __restrict__ Wg,
                                          int brow, int bcol,
                                          u16* As, u16* Bs, f32x4 acc[4][4]) {
  const int tid  = threadIdx.x;
  const int w    = tid >> 6;
  const int lane = tid & 63;
  const int q = lane & 15, g = lane >> 4;
  const int wm = w >> 1, wn = w & 1;

  for (int kt = 0; kt < CC / 32; ++kt) {
    #pragma unroll
    for (int i = 0; i < 2; ++i) {
      int Lg  = i * 256 + tid;         // granule id (16B each); [128][32]bf16 = 512 granules
      int row = Lg >> 2, gc = Lg & 3;
      gload_lds16(Ag + (brow + row) * CC + kt * 32 + gc * 8, As + (i * 256 + w * 64) * 8);
      gload_lds16(Wg + (bcol + row) * CC + kt * 32 + gc * 8, Bs + (i * 256 + w * 64) * 8);
    }
    __syncthreads();
    bf16x8 af[4], bff[4];
    #pragma unroll
    for (int a = 0; a < 4; ++a) af[a]  = *(const bf16x8*)&As[(wm * 64 + a * 16 + q) * 32 + g * 8];
    #pragma unroll
    for (int b = 0; b < 4; ++b) bff[b] = *(const bf16x8*)&Bs[(wn * 64 + b * 16 + q) * 32 + g * 8];
    #pragma unroll
    for (int a = 0; a < 4; ++a) {
      #pragma unroll
      for (int b = 0; b < 4; ++b) {
        acc[a][b] = __builtin_amdgcn_mfma_f32_16x16x32_bf16(af[a], bff[b], acc[a][b], 0, 0, 0);
      }
    }
    __syncthreads();
  }
}

// ---------------- kernel 1: QKV projection -> Q,K (B,H,T,D) and V^T (B,H,D,T) ------
__global__ __launch_bounds__(256)
void k_gemm_qkv(const u16* __restrict__ xb, const u16* __restrict__ wb,
                const float* __restrict__ sq, const float* __restrict__ bq,
                const float* __restrict__ sk, const float* __restrict__ bk,
                const float* __restrict__ sv, const float* __restrict__ bv,
                u16* __restrict__ Qo, u16* __restrict__ Ko, u16* __restrict__ Vt) {
  __shared__ u16 As[128 * 32];
  __shared__ u16 Bs[128 * 32];
  const int bid  = blockIdx.x;
  const int brow = (bid & 31) * 128;
  const int ncol = (bid >> 5) * 128;   // 0..3071
  const int mat  = ncol >> 10;
  const int bcol = ncol & 1023;
  const u16* W = wb + (mat << 20);

  f32x4 acc[4][4];
  #pragma unroll
  for (int a = 0; a < 4; ++a)
    #pragma unroll
    for (int b = 0; b < 4; ++b) { f32x4 z = {0.f, 0.f, 0.f, 0.f}; acc[a][b] = z; }

  gemm_core(xb, W, brow, bcol, As, Bs, acc);

  const int tid = threadIdx.x;
  const int w = tid >> 6, lane = tid & 63;
  const int q = lane & 15, g = lane >> 4;
  const int wm = w >> 1, wn = w & 1;
  const float* sarr = (mat == 0) ? sq : (mat == 1) ? sk : sv;
  const float* barr = (mat == 0) ? bq : (mat == 1) ? bk : bv;

  #pragma unroll
  for (int bt = 0; bt < 4; ++bt) {
    const int c = bcol + wn * 64 + bt * 16 + q;   // channel within matrix, 0..1023
    const float sc = sarr[c];
    const float bi = barr[c];
    const int h = c >> 6, d = c & 63;
    #pragma unroll
    for (int a = 0; a < 4; ++a) {
      #pragma unroll
      for (int r = 0; r < 4; ++r) {
        const int m = brow + wm * 64 + a * 16 + 4 * g + r;  // token row 0..4095
        const int b_ = m >> 11, t = m & 2047;
        const u16 val = f2bf(acc[a][bt][r] * sc + bi);
        if (mat == 0)      Qo[(((size_t)(b_ * HH + h) * TT) + t) * DD + d] = val;
        else if (mat == 1) Ko[(((size_t)(b_ * HH + h) * TT) + t) * DD + d] = val;
        else               Vt[((size_t)(b_ * HH + h) * DD + d) * TT + t] = val;  // V^T direct
      }
    }
  }
}

// ---------------- kernel 2: causal flash attention (QBLK=32/wave, KVBLK=64) ---------
// Swapped QK^T: S^T = K*Q^T so softmax row q is lane-local (col = lane&15).
// PV: O^T = V^T * P^T. K/V direct from global (L2-resident). Waves independent.
__global__ __launch_bounds__(256)
void k_attn(const u16* __restrict__ Q, const u16* __restrict__ K,
            const u16* __restrict__ Vt, u16* __restrict__ Y) {
  __shared__ u16 pbuf[4][32 * 72];   // per-wave P[qrow 0..31][key 0..63], stride 72
  const int tid = threadIdx.x;
  const int w = tid >> 6, lane = tid & 63;
  const int q = lane & 15, g = lane >> 4;
  const int bid = blockIdx.x;
  const int bh = bid & 31;                       // 0..31
  const int i_ = bid >> 5;                       // 0..15
  const int qb = (i_ < 8) ? i_ : (23 - i_);      // pair low/high q-blocks across CUs
  const int qbase = qb * 128 + w * 32;           // this wave's 32 q-rows
  const u16* Qh = Q  + (size_t)bh * TT * DD;
  const u16* Kh = K  + (size_t)bh * TT * DD;
  const u16* Vh = Vt + (size_t)bh * DD * TT;
  u16* pl = pbuf[w];

  // Q fragments: qf[j][s] = Q[qbase+16j+q][32s + 8g .. +8]
  bf16x8 qf[2][2];
  #pragma unroll
  for (int j = 0; j < 2; ++j)
    #pragma unroll
    for (int s = 0; s < 2; ++s)
      qf[j][s] = *(const bf16x8*)&Qh[(qbase + 16 * j + q) * DD + 32 * s + 8 * g];

  f32x4 oacc[4][2];   // O^T[dtile][qtile]
  #pragma unroll
  for (int dt = 0; dt < 4; ++dt)
    #pragma unroll
    for (int j = 0; j < 2; ++j) { f32x4 z = {0.f, 0.f, 0.f, 0.f}; oacc[dt][j] = z; }
  float m_run[2] = {-__builtin_inff(), -__builtin_inff()};
  float l_run[2] = {0.f, 0.f};
  const int nkb = (qbase + 95) >> 6;   // 64-key blocks covering keys 0..qbase+31
  constexpr float SE = 0.125f * 1.44269504088896340736f;  // scale * log2(e)

  for (int kb = 0; kb < nkb; ++kb) {
    const int kbase = kb * 64;
    // ---- QK^T: S^T[64k][32q] ----
    bf16x8 kf[4][2];
    #pragma unroll
    for (int t = 0; t < 4; ++t)
      #pragma unroll
      for (int s = 0; s < 2; ++s)
        kf[t][s] = *(const bf16x8*)&Kh[(kbase + 16 * t + q) * DD + 32 * s + 8 * g];
    f32x4 sacc[2][4];
    #pragma unroll
    for (int j = 0; j < 2; ++j)
      #pragma unroll
      for (int t = 0; t < 4; ++t) { f32x4 z = {0.f, 0.f, 0.f, 0.f}; sacc[j][t] = z; }
    __builtin_amdgcn_s_setprio(1);
    #pragma unroll
    for (int t = 0; t < 4; ++t)
      #pragma unroll
      for (int s = 0; s < 2; ++s) {
        sacc[0][t] = __builtin_amdgcn_mfma_f32_16x16x32_bf16(kf[t][s], qf[0][s], sacc[0][t], 0, 0, 0);
        sacc[1][t] = __builtin_amdgcn_mfma_f32_16x16x32_bf16(kf[t][s], qf[1][s], sacc[1][t], 0, 0, 0);
      }
    __builtin_amdgcn_s_setprio(0);

    // ---- softmax per q-tile, P -> wave-local LDS ----
    #pragma unroll
    for (int j = 0; j < 2; ++j) {
      const int qg = qbase + 16 * j + q;         // this lane's q-row for tile j
      float sv[16];
      #pragma unroll
      for (int t = 0; t < 4; ++t)
        #pragma unroll
        for (int r = 0; r < 4; ++r) sv[t * 4 + r] = sacc[j][t][r] * SE;
      if (kbase + 63 > qbase + 16 * j) {         // partial/causal region for this tile
        #pragma unroll
        for (int t = 0; t < 4; ++t)
          #pragma unroll
          for (int r = 0; r < 4; ++r)
            if (kbase + 16 * t + 4 * g + r > qg) sv[t * 4 + r] = -__builtin_inff();
      }
      float pmax = sv[0];
      #pragma unroll
      for (int u = 1; u < 16; ++u) pmax = fmaxf(pmax, sv[u]);
      pmax = fmaxf(pmax, __shfl_xor(pmax, 16));
      pmax = fmaxf(pmax, __shfl_xor(pmax, 32));
      const float m_new = fmaxf(m_run[j], pmax);
      const float alpha = __builtin_amdgcn_exp2f(m_run[j] - m_new);
      float p[16]; float psum = 0.f;
      #pragma unroll
      for (int u = 0; u < 16; ++u) { p[u] = __builtin_amdgcn_exp2f(sv[u] - m_new); psum += p[u]; }
      l_run[j] = l_run[j] * alpha + psum;
      m_run[j] = m_new;
      #pragma unroll
      for (int dt = 0; dt < 4; ++dt) oacc[dt][j] *= alpha;
      #pragma unroll
      for (int t = 0; t < 4; ++t) {
        u32 lo = (u32)f2bf(p[t * 4 + 0]) | ((u32)f2bf(p[t * 4 + 1]) << 16);
        u32 hi = (u32)f2bf(p[t * 4 + 2]) | ((u32)f2bf(p[t * 4 + 3]) << 16);
        *(uint2*)&pl[(16 * j + q) * 72 + 16 * t + 4 * g] = make_uint2(lo, hi);
      }
    }
    asm volatile("s_waitcnt lgkmcnt(0)" ::: "memory");
    __builtin_amdgcn_sched_barrier(0);

    // ---- PV: O^T[64d][32q] += V^T[64d][64k] * P^T[64k][32q] ----
    bf16x8 pf[2][2];
    #pragma unroll
    for (int j = 0; j < 2; ++j)
      #pragma unroll
      for (int s = 0; s < 2; ++s)
        pf[j][s] = *(const bf16x8*)&pl[(16 * j + q) * 72 + 32 * s + 8 * g];
    __builtin_amdgcn_s_setprio(1);
    #pragma unroll
    for (int s = 0; s < 2; ++s)
      #pragma unroll
      for (int dt = 0; dt < 4; ++dt) {
        bf16x8 vf = *(const bf16x8*)&Vh[(dt * 16 + q) * TT + kbase + 32 * s + 8 * g];
        oacc[dt][0] = __builtin_amdgcn_mfma_f32_16x16x32_bf16(vf, pf[0][s], oacc[dt][0], 0, 0, 0);
        oacc[dt][1] = __builtin_amdgcn_mfma_f32_16x16x32_bf16(vf, pf[1][s], oacc[dt][1], 0, 0, 0);
      }
    __builtin_amdgcn_s_setprio(0);
  }

  // ---- epilogue: normalize, write Y[b][t][h*64+d] ----
  const int b_ = bh >> 4, h = bh & 15;
  #pragma unroll
  for (int j = 0; j < 2; ++j) {
    float lt = l_run[j];
    lt += __shfl_xor(lt, 16);
    lt += __shfl_xor(lt, 32);
    const float inv = 1.f / (lt + 1e-8f);
    const int trow = qbase + 16 * j + q;
    #pragma unroll
    for (int dt = 0; dt < 4; ++dt) {
      u32 lo = (u32)f2bf(oacc[dt][j][0] * inv) | ((u32)f2bf(oacc[dt][j][1] * inv) << 16);
      u32 hi = (u32)f2bf(oacc[dt][j][2] * inv) | ((u32)f2bf(oacc[dt][j][3] * inv) << 16);
      *(uint2*)&Y[(size_t)(b_ * TT + trow) * CC + h * 64 + dt * 16 + 4 * g] = make_uint2(lo, hi);
    }
  }
}

// ---------------- kernel 3: output projection -> fp32 d_out -------------------------
__global__ __launch_bounds__(256)
void k_gemm_o(const u16* __restrict__ Yb, const u16* __restrict__ Wo,
              const float* __restrict__ so, const float* __restrict__ bo,
              float* __restrict__ out) {
  __shared__ u16 As[128 * 32];
  __shared__ u16 Bs[128 * 32];
  const int bid = blockIdx.x;
  const int brow = (bid & 31) * 128;
  const int bcol = (bid >> 5) * 128;
  f32x4 acc[4][4];
  #pragma unroll
  for (int a = 0; a < 4; ++a)
    #pragma unroll
    for (int b = 0; b < 4; ++b) { f32x4 z = {0.f, 0.f, 0.f, 0.f}; acc[a][b] = z; }

  gemm_core(Yb, Wo, brow, bcol, As, Bs, acc);

  const int tid = threadIdx.x;
  const int w = tid >> 6, lane = tid & 63;
  const int q = lane & 15, g = lane >> 4;
  const int wm = w >> 1, wn = w & 1;
  #pragma unroll
  for (int bt = 0; bt < 4; ++bt) {
    const int c = bcol + wn * 64 + bt * 16 + q;
    const float sc = so[c], bi = bo[c];
    #pragma unroll
    for (int a = 0; a < 4; ++a) {
      const int mbase = brow + wm * 64 + a * 16 + 4 * g;
      #pragma unroll
      for (int r = 0; r < 4; ++r) {
        out[(size_t)(mbase + r) * CC + c] = acc[a][bt][r] * sc + bi;
      }
    }
  }
}

// ---------------- launcher -----------------------------------------------------------
extern "C" void kernel_launch(void* const* d_in, const int* in_sizes, int n_in,
                              void* d_out, int out_size, void* d_ws, size_t ws_size,
                              hipStream_t stream) {
  const float* x  = (const float*)d_in[0];
  const void*  wq = d_in[1];
  const float* sq = (const float*)d_in[2];
  const float* bq = (const float*)d_in[3];
  const void*  wk = d_in[4];
  const float* sk = (const float*)d_in[5];
  const float* bk = (const float*)d_in[6];
  const void*  wv = d_in[7];
  const float* sv = (const float*)d_in[8];
  const float* bv = (const float*)d_in[9];
  const void*  wo = d_in[10];
  const float* so = (const float*)d_in[11];
  const float* bo = (const float*)d_in[12];

  const size_t NEED = (40u << 20) + 4096;
  if (ws_size < NEED) {   // diagnostic: error magnitude ~9999 => scratch too small
    k_sentinel<<<dim3((out_size + 255) / 256), dim3(256), 0, stream>>>((float*)d_out, out_size);
    return;
  }

  char* ws = (char*)d_ws;
  u16* xb = (u16*)(ws);                      // 8 MB  (x bf16; reused as Y later)
  u16* wb = (u16*)(ws + (8u  << 20));        // 8 MB  (4 weight matrices bf16)
  u16* Qb = (u16*)(ws + (16u << 20));        // 8 MB
  u16* Kb = (u16*)(ws + (24u << 20));        // 8 MB
  u16* Vt = (u16*)(ws + (32u << 20));        // 8 MB  (V^T, written directly by QKV GEMM)
  int* flag = (int*)(ws + (40u << 20));      // 4 B
  u16* Yb = xb;                              // x dead after QKV GEMM

  k_detect  <<<dim3(1),    dim3(256), 0, stream>>>((const int*)wq, flag);
  k_convert <<<dim3(8192), dim3(256), 0, stream>>>(x, wq, wk, wv, wo, flag, xb, wb);
  k_gemm_qkv<<<dim3(768),  dim3(256), 0, stream>>>(xb, wb, sq, bq, sk, bk, sv, bv, Qb, Kb, Vt);
  k_attn    <<<dim3(512),  dim3(256), 0, stream>>>(Qb, Kb, Vt, Yb);
  k_gemm_o  <<<dim3(256),  dim3(256), 0, stream>>>(Yb, wb + (3u << 20), so, bo, (float*)d_out);
}

// Round 4
// 148.227 us; speedup vs baseline: 2.0198x; 1.0052x over previous
//
#include <hip/hip_runtime.h>
#include <hip/hip_bf16.h>
#include <stdint.h>

#define BB 2
#define TT 2048
#define CC 1024
#define HH 16
#define DD 64
#define MM (BB*TT)   // 4096 rows

typedef __bf16 bf16x8 __attribute__((ext_vector_type(8)));
typedef float  f32x4  __attribute__((ext_vector_type(4)));
typedef unsigned short u16;
typedef unsigned int   u32;

// float -> bf16 bits, RTNE
__device__ __forceinline__ u16 f2bf(float f) {
  u32 u = __float_as_uint(f);
  return (u16)((u + 0x7fffu + ((u >> 16) & 1u)) >> 16);
}

// packed f32x2 -> bf16x2 (single VALU op; RTNE) [T12]
__device__ __forceinline__ u32 cvt_pk_bf16(float a, float b) {
  u32 r;
  asm("v_cvt_pk_bf16_f32 %0, %1, %2" : "=v"(r) : "v"(a), "v"(b));
  return r;
}

// async global->LDS, 16B per lane. LDS dest is wave-uniform base (+lane*16 by HW).
__device__ __forceinline__ void gload_lds16(const u16* g, u16* l) {
  auto gp = (const u32 __attribute__((address_space(1)))*)(uintptr_t)g;
  auto lp = (u32 __attribute__((address_space(3)))*)(u32)(uintptr_t)l;
  __builtin_amdgcn_global_load_lds(gp, lp, 16, 0, 0);
}

// ---------------- kernel S: sentinel (ws too small -> diagnostic output) ------------
__global__ __launch_bounds__(256)
void k_sentinel(float* __restrict__ out, int n) {
  int i = blockIdx.x * 256 + threadIdx.x;
  if (i < n) out[i] = 9999.0f;
}

// ---------------- kernel 0: convert x fp32->bf16, weights int32->bf16 (exact) ------
__global__ __launch_bounds__(256)
void k_convert(const float* __restrict__ x,
               const int* __restrict__ w0, const int* __restrict__ w1,
               const int* __restrict__ w2, const int* __restrict__ w3,
               u16* __restrict__ xb, u16* __restrict__ wb) {
  const int idx = blockIdx.x * 256 + threadIdx.x;
  const int NX = MM * CC / 4;          // 1048576 float4 units
  if (idx < NX) {
    float4 v = ((const float4*)x)[idx];
    u32 lo = (u32)f2bf(v.x) | ((u32)f2bf(v.y) << 16);
    u32 hi = (u32)f2bf(v.z) | ((u32)f2bf(v.w) << 16);
    ((uint2*)xb)[idx] = make_uint2(lo, hi);
  } else {
    int u = idx - NX;                  // 0..1048575 ; 262144 4-weight units per matrix
    int mat = u >> 18;
    int j = u & 262143;
    const int* ws = (mat == 0) ? w0 : (mat == 1) ? w1 : (mat == 2) ? w2 : w3;
    int4 v = ((const int4*)ws)[j];     // weights presented as int32 (confirmed R2)
    u32 lo = (u32)f2bf((float)v.x) | ((u32)f2bf((float)v.y) << 16);
    u32 hi = (u32)f2bf((float)v.z) | ((u32)f2bf((float)v.w) << 16);
    ((uint2*)wb)[(mat << 18) + j] = make_uint2(lo, hi);
  }
}

// ---------------- shared GEMM core: C[128x128] = A[128xK] * W[128xK]^T --------------
__device__ __forceinline__ void gemm_core(const u16* __restrict__ Ag,
                                          const u16* __restrict__ Wg,
                                          int brow, int bcol,
                                          u16* As, u16* Bs, f32x4 acc[4][4]) {
  const int tid  = threadIdx.x;
  const int w    = tid >> 6;
  const int lane = tid & 63;
  const int q = lane & 15, g = lane >> 4;
  const int wm = w >> 1, wn = w & 1;

  for (int kt = 0; kt < CC / 32; ++kt) {
    #pragma unroll
    for (int i = 0; i < 2; ++i) {
      int Lg  = i * 256 + tid;         // granule id (16B each); [128][32]bf16 = 512 granules
      int row = Lg >> 2, gc = Lg & 3;
      gload_lds16(Ag + (brow + row) * CC + kt * 32 + gc * 8, As + (i * 256 + w * 64) * 8);
      gload_lds16(Wg + (bcol + row) * CC + kt * 32 + gc * 8, Bs + (i * 256 + w * 64) * 8);
    }
    __syncthreads();
    bf16x8 af[4], bff[4];
    #pragma unroll
    for (int a = 0; a < 4; ++a) af[a]  = *(const bf16x8*)&As[(wm * 64 + a * 16 + q) * 32 + g * 8];
    #pragma unroll
    for (int b = 0; b < 4; ++b) bff[b] = *(const bf16x8*)&Bs[(wn * 64 + b * 16 + q) * 32 + g * 8];
    #pragma unroll
    for (int a = 0; a < 4; ++a) {
      #pragma unroll
      for (int b = 0; b < 4; ++b) {
        acc[a][b] = __builtin_amdgcn_mfma_f32_16x16x32_bf16(af[a], bff[b], acc[a][b], 0, 0, 0);
      }
    }
    __syncthreads();
  }
}

// ---------------- kernel 1: QKV projection -> Q,K (B,H,T,D) and V^T (B,H,D,T) ------
__global__ __launch_bounds__(256)
void k_gemm_qkv(const u16* __restrict__ xb, const u16* __restrict__ wb,
                const float* __restrict__ sq, const float* __restrict__ bq,
                const float* __restrict__ sk, const float* __restrict__ bk,
                const float* __restrict__ sv, const float* __restrict__ bv,
                u16* __restrict__ Qo, u16* __restrict__ Ko, u16* __restrict__ Vt) {
  __shared__ u16 As[128 * 32];
  __shared__ u16 Bs[128 * 32];
  const int bid  = blockIdx.x;
  const int brow = (bid & 31) * 128;
  const int ncol = (bid >> 5) * 128;   // 0..3071
  const int mat  = ncol >> 10;
  const int bcol = ncol & 1023;
  const u16* W = wb + (mat << 20);

  f32x4 acc[4][4];
  #pragma unroll
  for (int a = 0; a < 4; ++a)
    #pragma unroll
    for (int b = 0; b < 4; ++b) { f32x4 z = {0.f, 0.f, 0.f, 0.f}; acc[a][b] = z; }

  gemm_core(xb, W, brow, bcol, As, Bs, acc);

  const int tid = threadIdx.x;
  const int w = tid >> 6, lane = tid & 63;
  const int q = lane & 15, g = lane >> 4;
  const int wm = w >> 1, wn = w & 1;
  const float* sarr = (mat == 0) ? sq : (mat == 1) ? sk : sv;
  const float* barr = (mat == 0) ? bq : (mat == 1) ? bk : bv;

  #pragma unroll
  for (int bt = 0; bt < 4; ++bt) {
    const int c = bcol + wn * 64 + bt * 16 + q;   // channel within matrix, 0..1023
    const float sc = sarr[c];
    const float bi = barr[c];
    const int h = c >> 6, d = c & 63;
    #pragma unroll
    for (int a = 0; a < 4; ++a) {
      #pragma unroll
      for (int r = 0; r < 4; ++r) {
        const int m = brow + wm * 64 + a * 16 + 4 * g + r;  // token row 0..4095
        const int b_ = m >> 11, t = m & 2047;
        const u16 val = f2bf(acc[a][bt][r] * sc + bi);
        if (mat == 0)      Qo[(((size_t)(b_ * HH + h) * TT) + t) * DD + d] = val;
        else if (mat == 1) Ko[(((size_t)(b_ * HH + h) * TT) + t) * DD + d] = val;
        else               Vt[((size_t)(b_ * HH + h) * DD + d) * TT + t] = val;  // V^T direct
      }
    }
  }
}

// ---------------- kernel 2: causal flash attention (pair KV-split) ------------------
// Block = 4 waves = 2 pairs. Each pair owns 32 q-rows; its 2 waves stride alternate
// 64-key blocks (kb = u, u+2, ...), each running an independent online softmax;
// merged once at the end via LDS (m,l,O) exchange. Swapped QK^T: S^T = K*Q^T so the
// softmax row q is lane-local. PV: O^T = V^T * P^T. K/V direct from global (L2-hot).
__global__ __launch_bounds__(256)
void k_attn(const u16* __restrict__ Q, const u16* __restrict__ K,
            const u16* __restrict__ Vt, u16* __restrict__ Y) {
  __shared__ u16 pbuf[4][32 * 72];     // per-wave P[qrow 0..31][key 0..63], stride 72
  __shared__ float mrg[2][64 * 37];    // per pair: lane slot = 32 O + 2 m + 2 l (stride 37)
  const int tid = threadIdx.x;
  const int w = tid >> 6, lane = tid & 63;
  const int q = lane & 15, g = lane >> 4;
  const int p_ = w >> 1, u_ = w & 1;             // pair id, wave-in-pair
  const int bid = blockIdx.x;
  const int bh = bid & 31;                       // head-batch 0..31 (low bits: XCD locality)
  const int grp = bid >> 5;                      // 0..31
  const int tile = (p_ == 0) ? grp : (63 - grp); // balanced q-tiles per block
  const int qbase = tile * 32;
  const u16* Qh = Q  + (size_t)bh * TT * DD;
  const u16* Kh = K  + (size_t)bh * TT * DD;
  const u16* Vh = Vt + (size_t)bh * DD * TT;
  u16* pl = pbuf[w];

  // Q fragments: qf[j][s] = Q[qbase+16j+q][32s + 8g .. +8]
  bf16x8 qf[2][2];
  #pragma unroll
  for (int j = 0; j < 2; ++j)
    #pragma unroll
    for (int s = 0; s < 2; ++s)
      qf[j][s] = *(const bf16x8*)&Qh[(qbase + 16 * j + q) * DD + 32 * s + 8 * g];

  f32x4 oacc[4][2];   // O^T[dtile][qtile]
  #pragma unroll
  for (int dt = 0; dt < 4; ++dt)
    #pragma unroll
    for (int j = 0; j < 2; ++j) { f32x4 z = {0.f, 0.f, 0.f, 0.f}; oacc[dt][j] = z; }
  float m_run[2] = {-__builtin_inff(), -__builtin_inff()};
  float l_run[2] = {0.f, 0.f};
  const int nkb = (qbase + 95) >> 6;   // 64-key blocks covering keys 0..qbase+31
  constexpr float SE = 0.125f * 1.44269504088896340736f;  // scale * log2(e)

  for (int kb = u_; kb < nkb; kb += 2) {
    const int kbase = kb * 64;
    // ---- QK^T: S^T[64k][32q] ----
    bf16x8 kf[4][2];
    #pragma unroll
    for (int t = 0; t < 4; ++t)
      #pragma unroll
      for (int s = 0; s < 2; ++s)
        kf[t][s] = *(const bf16x8*)&Kh[(kbase + 16 * t + q) * DD + 32 * s + 8 * g];
    f32x4 sacc[2][4];
    #pragma unroll
    for (int j = 0; j < 2; ++j)
      #pragma unroll
      for (int t = 0; t < 4; ++t) { f32x4 z = {0.f, 0.f, 0.f, 0.f}; sacc[j][t] = z; }
    __builtin_amdgcn_s_setprio(1);
    #pragma unroll
    for (int t = 0; t < 4; ++t)
      #pragma unroll
      for (int s = 0; s < 2; ++s) {
        sacc[0][t] = __builtin_amdgcn_mfma_f32_16x16x32_bf16(kf[t][s], qf[0][s], sacc[0][t], 0, 0, 0);
        sacc[1][t] = __builtin_amdgcn_mfma_f32_16x16x32_bf16(kf[t][s], qf[1][s], sacc[1][t], 0, 0, 0);
      }
    __builtin_amdgcn_s_setprio(0);

    // ---- softmax per q-tile (defer-max THR=8), P -> wave-local LDS ----
    #pragma unroll
    for (int j = 0; j < 2; ++j) {
      const int qg = qbase + 16 * j + q;         // this lane's q-row for tile j
      float sv[16];
      #pragma unroll
      for (int t = 0; t < 4; ++t)
        #pragma unroll
        for (int r = 0; r < 4; ++r) sv[t * 4 + r] = sacc[j][t][r] * SE;
      if (kbase + 63 > qbase + 16 * j) {         // partial/causal region for this tile
        #pragma unroll
        for (int t = 0; t < 4; ++t)
          #pragma unroll
          for (int r = 0; r < 4; ++r)
            if (kbase + 16 * t + 4 * g + r > qg) sv[t * 4 + r] = -__builtin_inff();
      }
      float pmax = sv[0];
      #pragma unroll
      for (int u = 1; u < 16; ++u) pmax = fmaxf(pmax, sv[u]);
      pmax = fmaxf(pmax, __shfl_xor(pmax, 16));
      pmax = fmaxf(pmax, __shfl_xor(pmax, 32));
      const float m_prev = m_run[j];
      const bool keep = __all(pmax <= m_prev + 8.0f);   // defer-max: P bounded by 2^8
      const float m_new = keep ? m_prev : fmaxf(m_prev, pmax);
      float p[16]; float psum = 0.f;
      #pragma unroll
      for (int u = 0; u < 16; ++u) { p[u] = __builtin_amdgcn_exp2f(sv[u] - m_new); psum += p[u]; }
      if (keep) {
        l_run[j] += psum;
      } else {
        const float alpha = __builtin_amdgcn_exp2f(m_prev - m_new);
        l_run[j] = l_run[j] * alpha + psum;
        m_run[j] = m_new;
        #pragma unroll
        for (int dt = 0; dt < 4; ++dt) oacc[dt][j] *= alpha;
      }
      #pragma unroll
      for (int t = 0; t < 4; ++t) {
        u32 lo = cvt_pk_bf16(p[t * 4 + 0], p[t * 4 + 1]);
        u32 hi = cvt_pk_bf16(p[t * 4 + 2], p[t * 4 + 3]);
        *(uint2*)&pl[(16 * j + q) * 72 + 16 * t + 4 * g] = make_uint2(lo, hi);
      }
    }
    asm volatile("s_waitcnt lgkmcnt(0)" ::: "memory");
    __builtin_amdgcn_sched_barrier(0);

    // ---- PV: O^T[64d][32q] += V^T[64d][64k] * P^T[64k][32q] ----
    bf16x8 pf[2][2];
    #pragma unroll
    for (int j = 0; j < 2; ++j)
      #pragma unroll
      for (int s = 0; s < 2; ++s)
        pf[j][s] = *(const bf16x8*)&pl[(16 * j + q) * 72 + 32 * s + 8 * g];
    __builtin_amdgcn_s_setprio(1);
    #pragma unroll
    for (int s = 0; s < 2; ++s)
      #pragma unroll
      for (int dt = 0; dt < 4; ++dt) {
        bf16x8 vf = *(const bf16x8*)&Vh[(dt * 16 + q) * TT + kbase + 32 * s + 8 * g];
        oacc[dt][0] = __builtin_amdgcn_mfma_f32_16x16x32_bf16(vf, pf[0][s], oacc[dt][0], 0, 0, 0);
        oacc[dt][1] = __builtin_amdgcn_mfma_f32_16x16x32_bf16(vf, pf[1][s], oacc[dt][1], 0, 0, 0);
      }
    __builtin_amdgcn_s_setprio(0);
  }

  // ---- pair merge: wave u=1 publishes (O,m,l); wave u=0 combines + writes ----
  float* ms = &mrg[p_][lane * 37];
  if (u_ == 1) {
    #pragma unroll
    for (int dt = 0; dt < 4; ++dt)
      #pragma unroll
      for (int j = 0; j < 2; ++j)
        *(f32x4*)&ms[(dt * 2 + j) * 4] = oacc[dt][j];
    ms[32] = m_run[0]; ms[33] = m_run[1];
    ms[34] = l_run[0]; ms[35] = l_run[1];
  }
  __syncthreads();
  if (u_ == 0) {
    const int b_ = bh >> 4, h = bh & 15;
    #pragma unroll
    for (int j = 0; j < 2; ++j) {
      const float m1 = ms[32 + j], l1 = ms[34 + j];
      const float mt = fmaxf(m_run[j], m1);
      const float s0 = __builtin_amdgcn_exp2f(m_run[j] - mt);
      const float s1 = __builtin_amdgcn_exp2f(m1 - mt);      // m1=-inf -> 0
      float lt = l_run[j] * s0 + l1 * s1;
      lt += __shfl_xor(lt, 16);
      lt += __shfl_xor(lt, 32);
      const float inv = 1.f / (lt + 1e-8f);
      const int trow = qbase + 16 * j + q;
      #pragma unroll
      for (int dt = 0; dt < 4; ++dt) {
        f32x4 pv = *(const f32x4*)&ms[(dt * 2 + j) * 4];
        f32x4 om = oacc[dt][j] * s0 + pv * s1;
        u32 lo = cvt_pk_bf16(om[0] * inv, om[1] * inv);
        u32 hi = cvt_pk_bf16(om[2] * inv, om[3] * inv);
        *(uint2*)&Y[(size_t)(b_ * TT + trow) * CC + h * 64 + dt * 16 + 4 * g] = make_uint2(lo, hi);
      }
    }
  }
}

// ---------------- kernel 3: output projection -> fp32 d_out -------------------------
__global__ __launch_bounds__(256)
void k_gemm_o(const u16* __restrict__ Yb, const u16* __restrict__ Wo,
              const float* __restrict__ so, const float* __restrict__ bo,
              float* __restrict__ out) {
  __shared__ u16 As[128 * 32];
  __shared__ u16 Bs[128 * 32];
  const int bid = blockIdx.x;
  const int brow = (bid & 31) * 128;
  const int bcol = (bid >> 5) * 128;
  f32x4 acc[4][4];
  #pragma unroll
  for (int a = 0; a < 4; ++a)
    #pragma unroll
    for (int b = 0; b < 4; ++b) { f32x4 z = {0.f, 0.f, 0.f, 0.f}; acc[a][b] = z; }

  gemm_core(Yb, Wo, brow, bcol, As, Bs, acc);

  const int tid = threadIdx.x;
  const int w = tid >> 6, lane = tid & 63;
  const int q = lane & 15, g = lane >> 4;
  const int wm = w >> 1, wn = w & 1;
  #pragma unroll
  for (int bt = 0; bt < 4; ++bt) {
    const int c = bcol + wn * 64 + bt * 16 + q;
    const float sc = so[c], bi = bo[c];
    #pragma unroll
    for (int a = 0; a < 4; ++a) {
      const int mbase = brow + wm * 64 + a * 16 + 4 * g;
      #pragma unroll
      for (int r = 0; r < 4; ++r) {
        out[(size_t)(mbase + r) * CC + c] = acc[a][bt][r] * sc + bi;
      }
    }
  }
}

// ---------------- launcher -----------------------------------------------------------
extern "C" void kernel_launch(void* const* d_in, const int* in_sizes, int n_in,
                              void* d_out, int out_size, void* d_ws, size_t ws_size,
                              hipStream_t stream) {
  const float* x  = (const float*)d_in[0];
  const int*   wq = (const int*)d_in[1];
  const float* sq = (const float*)d_in[2];
  const float* bq = (const float*)d_in[3];
  const int*   wk = (const int*)d_in[4];
  const float* sk = (const float*)d_in[5];
  const float* bk = (const float*)d_in[6];
  const int*   wv = (const int*)d_in[7];
  const float* sv = (const float*)d_in[8];
  const float* bv = (const float*)d_in[9];
  const int*   wo = (const int*)d_in[10];
  const float* so = (const float*)d_in[11];
  const float* bo = (const float*)d_in[12];

  const size_t NEED = (40u << 20);
  if (ws_size < NEED) {   // diagnostic: error magnitude ~9999 => scratch too small
    k_sentinel<<<dim3((out_size + 255) / 256), dim3(256), 0, stream>>>((float*)d_out, out_size);
    return;
  }

  char* ws = (char*)d_ws;
  u16* xb = (u16*)(ws);                      // 8 MB  (x bf16; reused as Y later)
  u16* wb = (u16*)(ws + (8u  << 20));        // 8 MB  (4 weight matrices bf16)
  u16* Qb = (u16*)(ws + (16u << 20));        // 8 MB
  u16* Kb = (u16*)(ws + (24u << 20));        // 8 MB
  u16* Vt = (u16*)(ws + (32u << 20));        // 8 MB  (V^T, written directly by QKV GEMM)
  u16* Yb = xb;                              // x dead after QKV GEMM

  k_convert <<<dim3(8192), dim3(256), 0, stream>>>(x, wq, wk, wv, wo, xb, wb);
  k_gemm_qkv<<<dim3(768),  dim3(256), 0, stream>>>(xb, wb, sq, bq, sk, bk, sv, bv, Qb, Kb, Vt);
  k_attn    <<<dim3(1024), dim3(256), 0, stream>>>(Qb, Kb, Vt, Yb);
  k_gemm_o  <<<dim3(256),  dim3(256), 0, stream>>>(Yb, wb + (3u << 20), so, bo, (float*)d_out);
}

// Round 5
// 143.307 us; speedup vs baseline: 2.0892x; 1.0343x over previous
//
#include <hip/hip_runtime.h>
#include <hip/hip_bf16.h>
#include <stdint.h>

#define BB 2
#define TT 2048
#define CC 1024
#define HH 16
#define DD 64
#define MM (BB*TT)   // 4096 rows

typedef __bf16 bf16x8 __attribute__((ext_vector_type(8)));
typedef float  f32x4  __attribute__((ext_vector_type(4)));
typedef unsigned short u16;
typedef unsigned int   u32;

// float -> bf16 bits, RTNE
__device__ __forceinline__ u16 f2bf(float f) {
  u32 u = __float_as_uint(f);
  return (u16)((u + 0x7fffu + ((u >> 16) & 1u)) >> 16);
}

// packed f32x2 -> bf16x2 (single VALU op; RTNE) [T12]
__device__ __forceinline__ u32 cvt_pk_bf16(float a, float b) {
  u32 r;
  asm("v_cvt_pk_bf16_f32 %0, %1, %2" : "=v"(r) : "v"(a), "v"(b));
  return r;
}

// async global->LDS, 16B per lane. LDS dest is wave-uniform base (+lane*16 by HW).
__device__ __forceinline__ void gload_lds16(const u16* g, u16* l) {
  auto gp = (const u32 __attribute__((address_space(1)))*)(uintptr_t)g;
  auto lp = (u32 __attribute__((address_space(3)))*)(u32)(uintptr_t)l;
  __builtin_amdgcn_global_load_lds(gp, lp, 16, 0, 0);
}

// ---------------- kernel S: sentinel (ws too small -> diagnostic output) ------------
__global__ __launch_bounds__(256)
void k_sentinel(float* __restrict__ out, int n) {
  int i = blockIdx.x * 256 + threadIdx.x;
  if (i < n) out[i] = 9999.0f;
}

// ---------------- kernel 0: convert x fp32->bf16, weights int32->bf16 (exact) ------
__global__ __launch_bounds__(256)
void k_convert(const float* __restrict__ x,
               const int* __restrict__ w0, const int* __restrict__ w1,
               const int* __restrict__ w2, const int* __restrict__ w3,
               u16* __restrict__ xb, u16* __restrict__ wb) {
  const int idx = blockIdx.x * 256 + threadIdx.x;
  const int NX = MM * CC / 4;          // 1048576 float4 units
  if (idx < NX) {
    float4 v = ((const float4*)x)[idx];
    u32 lo = (u32)f2bf(v.x) | ((u32)f2bf(v.y) << 16);
    u32 hi = (u32)f2bf(v.z) | ((u32)f2bf(v.w) << 16);
    ((uint2*)xb)[idx] = make_uint2(lo, hi);
  } else {
    int u = idx - NX;                  // 0..1048575 ; 262144 4-weight units per matrix
    int mat = u >> 18;
    int j = u & 262143;
    const int* ws = (mat == 0) ? w0 : (mat == 1) ? w1 : (mat == 2) ? w2 : w3;
    int4 v = ((const int4*)ws)[j];     // weights presented as int32 (confirmed R2)
    u32 lo = (u32)f2bf((float)v.x) | ((u32)f2bf((float)v.y) << 16);
    u32 hi = (u32)f2bf((float)v.z) | ((u32)f2bf((float)v.w) << 16);
    ((uint2*)wb)[(mat << 18) + j] = make_uint2(lo, hi);
  }
}

// ---------------- shared GEMM core: C[128x128] = A[128xK] * W[128xK]^T --------------
__device__ __forceinline__ void gemm_core(const u16* __restrict__ Ag,
                                          const u16* __restrict__ Wg,
                                          int brow, int bcol,
                                          u16* As, u16* Bs, f32x4 acc[4][4]) {
  const int tid  = threadIdx.x;
  const int w    = tid >> 6;
  const int lane = tid & 63;
  const int q = lane & 15, g = lane >> 4;
  const int wm = w >> 1, wn = w & 1;

  for (int kt = 0; kt < CC / 32; ++kt) {
    #pragma unroll
    for (int i = 0; i < 2; ++i) {
      int Lg  = i * 256 + tid;         // granule id (16B each); [128][32]bf16 = 512 granules
      int row = Lg >> 2, gc = Lg & 3;
      gload_lds16(Ag + (brow + row) * CC + kt * 32 + gc * 8, As + (i * 256 + w * 64) * 8);
      gload_lds16(Wg + (bcol + row) * CC + kt * 32 + gc * 8, Bs + (i * 256 + w * 64) * 8);
    }
    __syncthreads();
    bf16x8 af[4], bff[4];
    #pragma unroll
    for (int a = 0; a < 4; ++a) af[a]  = *(const bf16x8*)&As[(wm * 64 + a * 16 + q) * 32 + g * 8];
    #pragma unroll
    for (int b = 0; b < 4; ++b) bff[b] = *(const bf16x8*)&Bs[(wn * 64 + b * 16 + q) * 32 + g * 8];
    #pragma unroll
    for (int a = 0; a < 4; ++a) {
      #pragma unroll
      for (int b = 0; b < 4; ++b) {
        acc[a][b] = __builtin_amdgcn_mfma_f32_16x16x32_bf16(af[a], bff[b], acc[a][b], 0, 0, 0);
      }
    }
    __syncthreads();
  }
}

// ---------------- kernel 1: QKV projection -> Q,K (B,H,T,D) and V^T (B,H,D,T) ------
__global__ __launch_bounds__(256)
void k_gemm_qkv(const u16* __restrict__ xb, const u16* __restrict__ wb,
                const float* __restrict__ sq, const float* __restrict__ bq,
                const float* __restrict__ sk, const float* __restrict__ bk,
                const float* __restrict__ sv, const float* __restrict__ bv,
                u16* __restrict__ Qo, u16* __restrict__ Ko, u16* __restrict__ Vt) {
  __shared__ u16 As[128 * 32];
  __shared__ u16 Bs[128 * 32];
  const int bid  = blockIdx.x;
  const int brow = (bid & 31) * 128;
  const int ncol = (bid >> 5) * 128;   // 0..3071
  const int mat  = ncol >> 10;
  const int bcol = ncol & 1023;
  const u16* W = wb + (mat << 20);

  f32x4 acc[4][4];
  #pragma unroll
  for (int a = 0; a < 4; ++a)
    #pragma unroll
    for (int b = 0; b < 4; ++b) { f32x4 z = {0.f, 0.f, 0.f, 0.f}; acc[a][b] = z; }

  gemm_core(xb, W, brow, bcol, As, Bs, acc);

  const int tid = threadIdx.x;
  const int w = tid >> 6, lane = tid & 63;
  const int q = lane & 15, g = lane >> 4;
  const int wm = w >> 1, wn = w & 1;
  const float* sarr = (mat == 0) ? sq : (mat == 1) ? sk : sv;
  const float* barr = (mat == 0) ? bq : (mat == 1) ? bk : bv;

  #pragma unroll
  for (int bt = 0; bt < 4; ++bt) {
    const int c = bcol + wn * 64 + bt * 16 + q;   // channel within matrix, 0..1023
    const float sc = sarr[c];
    const float bi = barr[c];
    const int h = c >> 6, d = c & 63;
    #pragma unroll
    for (int a = 0; a < 4; ++a) {
      #pragma unroll
      for (int r = 0; r < 4; ++r) {
        const int m = brow + wm * 64 + a * 16 + 4 * g + r;  // token row 0..4095
        const int b_ = m >> 11, t = m & 2047;
        const u16 val = f2bf(acc[a][bt][r] * sc + bi);
        if (mat == 0)      Qo[(((size_t)(b_ * HH + h) * TT) + t) * DD + d] = val;
        else if (mat == 1) Ko[(((size_t)(b_ * HH + h) * TT) + t) * DD + d] = val;
        else               Vt[((size_t)(b_ * HH + h) * DD + d) * TT + t] = val;  // V^T direct
      }
    }
  }
}

// ---------------- kernel 2: causal flash attention (pair KV-split, pipelined) -------
// Block = 4 waves = 2 pairs. Each pair owns 32 q-rows; its 2 waves stride alternate
// 64-key blocks, each an independent online softmax, merged at the end via LDS.
// Loads are software-pipelined: V for the CURRENT block issues before QK^T; K for the
// NEXT block issues before softmax -- both latencies hide under MFMA+VALU work.
__global__ __launch_bounds__(256)
void k_attn(const u16* __restrict__ Q, const u16* __restrict__ K,
            const u16* __restrict__ Vt, u16* __restrict__ Y) {
  __shared__ u16 pbuf[4][32 * 72];     // per-wave P[qrow 0..31][key 0..63], stride 72
  __shared__ float mrg[2][64 * 37];    // per pair: lane slot = 32 O + 2 m + 2 l (stride 37)
  const int tid = threadIdx.x;
  const int w = tid >> 6, lane = tid & 63;
  const int q = lane & 15, g = lane >> 4;
  const int p_ = w >> 1, u_ = w & 1;             // pair id, wave-in-pair
  const int bid = blockIdx.x;
  const int bh = bid & 31;                       // head-batch 0..31 (low bits: XCD locality)
  const int grp = bid >> 5;                      // 0..31
  const int tile = (p_ == 0) ? grp : (63 - grp); // balanced q-tiles per block
  const int qbase = tile * 32;
  const u16* Qh = Q  + (size_t)bh * TT * DD;
  const u16* Kh = K  + (size_t)bh * TT * DD;
  const u16* Vh = Vt + (size_t)bh * DD * TT;
  u16* pl = pbuf[w];

  // Q fragments: qf[j][s] = Q[qbase+16j+q][32s + 8g .. +8]
  bf16x8 qf[2][2];
  #pragma unroll
  for (int j = 0; j < 2; ++j)
    #pragma unroll
    for (int s = 0; s < 2; ++s)
      qf[j][s] = *(const bf16x8*)&Qh[(qbase + 16 * j + q) * DD + 32 * s + 8 * g];

  f32x4 oacc[4][2];   // O^T[dtile][qtile]
  #pragma unroll
  for (int dt = 0; dt < 4; ++dt)
    #pragma unroll
    for (int j = 0; j < 2; ++j) { f32x4 z = {0.f, 0.f, 0.f, 0.f}; oacc[dt][j] = z; }
  float m_run[2] = {-__builtin_inff(), -__builtin_inff()};
  float l_run[2] = {0.f, 0.f};
  const int nkb = (qbase + 95) >> 6;   // 64-key blocks covering keys 0..qbase+31
  constexpr float SE = 0.125f * 1.44269504088896340736f;  // scale * log2(e)

  // prologue: K fragments for this wave's first block
  bf16x8 kf[4][2];
  #pragma unroll
  for (int t = 0; t < 4; ++t)
    #pragma unroll
    for (int s = 0; s < 2; ++s)
      kf[t][s] = *(const bf16x8*)&Kh[(u_ * 64 + 16 * t + q) * DD + 32 * s + 8 * g];

  for (int kb = u_; kb < nkb; kb += 2) {
    const int kbase = kb * 64;
    // ---- V loads for CURRENT block: issue first, consumed by PV at iteration end ----
    bf16x8 vf[2][4];
    #pragma unroll
    for (int s = 0; s < 2; ++s)
      #pragma unroll
      for (int dt = 0; dt < 4; ++dt)
        vf[s][dt] = *(const bf16x8*)&Vh[(dt * 16 + q) * TT + kbase + 32 * s + 8 * g];

    // ---- QK^T: S^T[64k][32q] ----
    f32x4 sacc[2][4];
    #pragma unroll
    for (int j = 0; j < 2; ++j)
      #pragma unroll
      for (int t = 0; t < 4; ++t) { f32x4 z = {0.f, 0.f, 0.f, 0.f}; sacc[j][t] = z; }
    __builtin_amdgcn_s_setprio(1);
    #pragma unroll
    for (int t = 0; t < 4; ++t)
      #pragma unroll
      for (int s = 0; s < 2; ++s) {
        sacc[0][t] = __builtin_amdgcn_mfma_f32_16x16x32_bf16(kf[t][s], qf[0][s], sacc[0][t], 0, 0, 0);
        sacc[1][t] = __builtin_amdgcn_mfma_f32_16x16x32_bf16(kf[t][s], qf[1][s], sacc[1][t], 0, 0, 0);
      }
    __builtin_amdgcn_s_setprio(0);

    // ---- K prefetch for NEXT block (latency hides under softmax + PV) ----
    // Tail prefetch may read <=20KB past this head's K rows -- lands in adjacent ws
    // buffer, values unused.
    #pragma unroll
    for (int t = 0; t < 4; ++t)
      #pragma unroll
      for (int s = 0; s < 2; ++s)
        kf[t][s] = *(const bf16x8*)&Kh[(kbase + 128 + 16 * t + q) * DD + 32 * s + 8 * g];

    // ---- softmax per q-tile (defer-max THR=8), P -> wave-local LDS ----
    #pragma unroll
    for (int j = 0; j < 2; ++j) {
      const int qg = qbase + 16 * j + q;         // this lane's q-row for tile j
      float sv[16];
      #pragma unroll
      for (int t = 0; t < 4; ++t)
        #pragma unroll
        for (int r = 0; r < 4; ++r) sv[t * 4 + r] = sacc[j][t][r] * SE;
      if (kbase + 63 > qbase + 16 * j) {         // partial/causal region for this tile
        #pragma unroll
        for (int t = 0; t < 4; ++t)
          #pragma unroll
          for (int r = 0; r < 4; ++r)
            if (kbase + 16 * t + 4 * g + r > qg) sv[t * 4 + r] = -__builtin_inff();
      }
      // max tree (depth 4)
      float m0 = fmaxf(sv[0], sv[1]),  m1 = fmaxf(sv[2], sv[3]);
      float m2 = fmaxf(sv[4], sv[5]),  m3 = fmaxf(sv[6], sv[7]);
      float m4 = fmaxf(sv[8], sv[9]),  m5 = fmaxf(sv[10], sv[11]);
      float m6 = fmaxf(sv[12], sv[13]), m7 = fmaxf(sv[14], sv[15]);
      float pmax = fmaxf(fmaxf(fmaxf(m0, m1), fmaxf(m2, m3)),
                         fmaxf(fmaxf(m4, m5), fmaxf(m6, m7)));
      pmax = fmaxf(pmax, __shfl_xor(pmax, 16));
      pmax = fmaxf(pmax, __shfl_xor(pmax, 32));
      const float m_prev = m_run[j];
      const bool keep = __all(pmax <= m_prev + 8.0f);   // defer-max: P bounded by 2^8
      const float m_new = keep ? m_prev : fmaxf(m_prev, pmax);
      float p[16];
      #pragma unroll
      for (int u = 0; u < 16; ++u) p[u] = __builtin_amdgcn_exp2f(sv[u] - m_new);
      // sum tree
      float s01 = (p[0] + p[1]) + (p[2] + p[3]);
      float s23 = (p[4] + p[5]) + (p[6] + p[7]);
      float s45 = (p[8] + p[9]) + (p[10] + p[11]);
      float s67 = (p[12] + p[13]) + (p[14] + p[15]);
      const float psum = (s01 + s23) + (s45 + s67);
      if (keep) {
        l_run[j] += psum;
      } else {
        const float alpha = __builtin_amdgcn_exp2f(m_prev - m_new);
        l_run[j] = l_run[j] * alpha + psum;
        m_run[j] = m_new;
        #pragma unroll
        for (int dt = 0; dt < 4; ++dt) oacc[dt][j] *= alpha;
      }
      #pragma unroll
      for (int t = 0; t < 4; ++t) {
        u32 lo = cvt_pk_bf16(p[t * 4 + 0], p[t * 4 + 1]);
        u32 hi = cvt_pk_bf16(p[t * 4 + 2], p[t * 4 + 3]);
        *(uint2*)&pl[(16 * j + q) * 72 + 16 * t + 4 * g] = make_uint2(lo, hi);
      }
    }
    asm volatile("s_waitcnt lgkmcnt(0)" ::: "memory");
    __builtin_amdgcn_sched_barrier(0);

    // ---- PV: O^T[64d][32q] += V^T[64d][64k] * P^T[64k][32q] ----
    bf16x8 pf[2][2];
    #pragma unroll
    for (int j = 0; j < 2; ++j)
      #pragma unroll
      for (int s = 0; s < 2; ++s)
        pf[j][s] = *(const bf16x8*)&pl[(16 * j + q) * 72 + 32 * s + 8 * g];
    __builtin_amdgcn_s_setprio(1);
    #pragma unroll
    for (int s = 0; s < 2; ++s)
      #pragma unroll
      for (int dt = 0; dt < 4; ++dt) {
        oacc[dt][0] = __builtin_amdgcn_mfma_f32_16x16x32_bf16(vf[s][dt], pf[0][s], oacc[dt][0], 0, 0, 0);
        oacc[dt][1] = __builtin_amdgcn_mfma_f32_16x16x32_bf16(vf[s][dt], pf[1][s], oacc[dt][1], 0, 0, 0);
      }
    __builtin_amdgcn_s_setprio(0);
  }

  // ---- pair merge: wave u=1 publishes (O,m,l); wave u=0 combines + writes ----
  float* ms = &mrg[p_][lane * 37];
  if (u_ == 1) {
    #pragma unroll
    for (int dt = 0; dt < 4; ++dt)
      #pragma unroll
      for (int j = 0; j < 2; ++j)
        *(f32x4*)&ms[(dt * 2 + j) * 4] = oacc[dt][j];
    ms[32] = m_run[0]; ms[33] = m_run[1];
    ms[34] = l_run[0]; ms[35] = l_run[1];
  }
  __syncthreads();
  if (u_ == 0) {
    const int b_ = bh >> 4, h = bh & 15;
    #pragma unroll
    for (int j = 0; j < 2; ++j) {
      const float m1 = ms[32 + j], l1 = ms[34 + j];
      const float mt = fmaxf(m_run[j], m1);
      const float s0 = __builtin_amdgcn_exp2f(m_run[j] - mt);
      const float s1 = __builtin_amdgcn_exp2f(m1 - mt);      // m1=-inf -> 0
      float lt = l_run[j] * s0 + l1 * s1;
      lt += __shfl_xor(lt, 16);
      lt += __shfl_xor(lt, 32);
      const float inv = 1.f / (lt + 1e-8f);
      const int trow = qbase + 16 * j + q;
      #pragma unroll
      for (int dt = 0; dt < 4; ++dt) {
        f32x4 pv = *(const f32x4*)&ms[(dt * 2 + j) * 4];
        f32x4 om = oacc[dt][j] * s0 + pv * s1;
        u32 lo = cvt_pk_bf16(om[0] * inv, om[1] * inv);
        u32 hi = cvt_pk_bf16(om[2] * inv, om[3] * inv);
        *(uint2*)&Y[(size_t)(b_ * TT + trow) * CC + h * 64 + dt * 16 + 4 * g] = make_uint2(lo, hi);
      }
    }
  }
}

// ---------------- kernel 3: output projection -> fp32 d_out -------------------------
__global__ __launch_bounds__(256)
void k_gemm_o(const u16* __restrict__ Yb, const u16* __restrict__ Wo,
              const float* __restrict__ so, const float* __restrict__ bo,
              float* __restrict__ out) {
  __shared__ u16 As[128 * 32];
  __shared__ u16 Bs[128 * 32];
  const int bid = blockIdx.x;
  const int brow = (bid & 31) * 128;
  const int bcol = (bid >> 5) * 128;
  f32x4 acc[4][4];
  #pragma unroll
  for (int a = 0; a < 4; ++a)
    #pragma unroll
    for (int b = 0; b < 4; ++b) { f32x4 z = {0.f, 0.f, 0.f, 0.f}; acc[a][b] = z; }

  gemm_core(Yb, Wo, brow, bcol, As, Bs, acc);

  const int tid = threadIdx.x;
  const int w = tid >> 6, lane = tid & 63;
  const int q = lane & 15, g = lane >> 4;
  const int wm = w >> 1, wn = w & 1;
  #pragma unroll
  for (int bt = 0; bt < 4; ++bt) {
    const int c = bcol + wn * 64 + bt * 16 + q;
    const float sc = so[c], bi = bo[c];
    #pragma unroll
    for (int a = 0; a < 4; ++a) {
      const int mbase = brow + wm * 64 + a * 16 + 4 * g;
      #pragma unroll
      for (int r = 0; r < 4; ++r) {
        out[(size_t)(mbase + r) * CC + c] = acc[a][bt][r] * sc + bi;
      }
    }
  }
}

// ---------------- launcher -----------------------------------------------------------
extern "C" void kernel_launch(void* const* d_in, const int* in_sizes, int n_in,
                              void* d_out, int out_size, void* d_ws, size_t ws_size,
                              hipStream_t stream) {
  const float* x  = (const float*)d_in[0];
  const int*   wq = (const int*)d_in[1];
  const float* sq = (const float*)d_in[2];
  const float* bq = (const float*)d_in[3];
  const int*   wk = (const int*)d_in[4];
  const float* sk = (const float*)d_in[5];
  const float* bk = (const float*)d_in[6];
  const int*   wv = (const int*)d_in[7];
  const float* sv = (const float*)d_in[8];
  const float* bv = (const float*)d_in[9];
  const int*   wo = (const int*)d_in[10];
  const float* so = (const float*)d_in[11];
  const float* bo = (const float*)d_in[12];

  const size_t NEED = (40u << 20);
  if (ws_size < NEED) {   // diagnostic: error magnitude ~9999 => scratch too small
    k_sentinel<<<dim3((out_size + 255) / 256), dim3(256), 0, stream>>>((float*)d_out, out_size);
    return;
  }

  char* ws = (char*)d_ws;
  u16* xb = (u16*)(ws);                      // 8 MB  (x bf16; reused as Y later)
  u16* wb = (u16*)(ws + (8u  << 20));        // 8 MB  (4 weight matrices bf16)
  u16* Qb = (u16*)(ws + (16u << 20));        // 8 MB
  u16* Kb = (u16*)(ws + (24u << 20));        // 8 MB
  u16* Vt = (u16*)(ws + (32u << 20));        // 8 MB  (V^T, written directly by QKV GEMM)
  u16* Yb = xb;                              // x dead after QKV GEMM

  k_convert <<<dim3(8192), dim3(256), 0, stream>>>(x, wq, wk, wv, wo, xb, wb);
  k_gemm_qkv<<<dim3(768),  dim3(256), 0, stream>>>(xb, wb, sq, bq, sk, bk, sv, bv, Qb, Kb, Vt);
  k_attn    <<<dim3(1024), dim3(256), 0, stream>>>(Qb, Kb, Vt, Yb);
  k_gemm_o  <<<dim3(256),  dim3(256), 0, stream>>>(Yb, wb + (3u << 20), so, bo, (float*)d_out);
}

// Round 6
// 137.020 us; speedup vs baseline: 2.1850x; 1.0459x over previous
//
#include <hip/hip_runtime.h>
#include <hip/hip_bf16.h>
#include <stdint.h>

#define BB 2
#define TT 2048
#define CC 1024
#define HH 16
#define DD 64
#define MM (BB*TT)   // 4096 rows

typedef __bf16 bf16x8 __attribute__((ext_vector_type(8)));
typedef float  f32x4  __attribute__((ext_vector_type(4)));
typedef float  f32x16 __attribute__((ext_vector_type(16)));
typedef unsigned short u16;
typedef unsigned int   u32;

// float -> bf16 bits, RTNE
__device__ __forceinline__ u16 f2bf(float f) {
  u32 u = __float_as_uint(f);
  return (u16)((u + 0x7fffu + ((u >> 16) & 1u)) >> 16);
}

// packed f32x2 -> bf16x2 (single VALU op; RTNE) [T12]
__device__ __forceinline__ u32 cvt_pk_bf16(float a, float b) {
  u32 r;
  asm("v_cvt_pk_bf16_f32 %0, %1, %2" : "=v"(r) : "v"(a), "v"(b));
  return r;
}

// async global->LDS, 16B per lane. LDS dest is wave-uniform base (+lane*16 by HW).
__device__ __forceinline__ void gload_lds16(const u16* g, u16* l) {
  auto gp = (const u32 __attribute__((address_space(1)))*)(uintptr_t)g;
  auto lp = (u32 __attribute__((address_space(3)))*)(u32)(uintptr_t)l;
  __builtin_amdgcn_global_load_lds(gp, lp, 16, 0, 0);
}

// ---------------- kernel S: sentinel (ws too small -> diagnostic output) ------------
__global__ __launch_bounds__(256)
void k_sentinel(float* __restrict__ out, int n) {
  int i = blockIdx.x * 256 + threadIdx.x;
  if (i < n) out[i] = 9999.0f;
}

// ---------------- kernel 0: convert x fp32->bf16, weights int32->bf16 (exact) ------
__global__ __launch_bounds__(256)
void k_convert(const float* __restrict__ x,
               const int* __restrict__ w0, const int* __restrict__ w1,
               const int* __restrict__ w2, const int* __restrict__ w3,
               u16* __restrict__ xb, u16* __restrict__ wb) {
  const int idx = blockIdx.x * 256 + threadIdx.x;
  const int NX = MM * CC / 4;          // 1048576 float4 units
  if (idx < NX) {
    float4 v = ((const float4*)x)[idx];
    u32 lo = (u32)f2bf(v.x) | ((u32)f2bf(v.y) << 16);
    u32 hi = (u32)f2bf(v.z) | ((u32)f2bf(v.w) << 16);
    ((uint2*)xb)[idx] = make_uint2(lo, hi);
  } else {
    int u = idx - NX;                  // 0..1048575 ; 262144 4-weight units per matrix
    int mat = u >> 18;
    int j = u & 262143;
    const int* ws = (mat == 0) ? w0 : (mat == 1) ? w1 : (mat == 2) ? w2 : w3;
    int4 v = ((const int4*)ws)[j];     // weights presented as int32 (confirmed R2)
    u32 lo = (u32)f2bf((float)v.x) | ((u32)f2bf((float)v.y) << 16);
    u32 hi = (u32)f2bf((float)v.z) | ((u32)f2bf((float)v.w) << 16);
    ((uint2*)wb)[(mat << 18) + j] = make_uint2(lo, hi);
  }
}

// ---------------- shared GEMM core: C[128x128] = A[128xK] * W[128xK]^T --------------
__device__ __forceinline__ void gemm_core(const u16* __restrict__ Ag,
                                          const u16* __restrict__ Wg,
                                          int brow, int bcol,
                                          u16* As, u16* Bs, f32x4 acc[4][4]) {
  const int tid  = threadIdx.x;
  const int w    = tid >> 6;
  const int lane = tid & 63;
  const int q = lane & 15, g = lane >> 4;
  const int wm = w >> 1, wn = w & 1;

  for (int kt = 0; kt < CC / 32; ++kt) {
    #pragma unroll
    for (int i = 0; i < 2; ++i) {
      int Lg  = i * 256 + tid;         // granule id (16B each); [128][32]bf16 = 512 granules
      int row = Lg >> 2, gc = Lg & 3;
      gload_lds16(Ag + (brow + row) * CC + kt * 32 + gc * 8, As + (i * 256 + w * 64) * 8);
      gload_lds16(Wg + (bcol + row) * CC + kt * 32 + gc * 8, Bs + (i * 256 + w * 64) * 8);
    }
    __syncthreads();
    bf16x8 af[4], bff[4];
    #pragma unroll
    for (int a = 0; a < 4; ++a) af[a]  = *(const bf16x8*)&As[(wm * 64 + a * 16 + q) * 32 + g * 8];
    #pragma unroll
    for (int b = 0; b < 4; ++b) bff[b] = *(const bf16x8*)&Bs[(wn * 64 + b * 16 + q) * 32 + g * 8];
    #pragma unroll
    for (int a = 0; a < 4; ++a) {
      #pragma unroll
      for (int b = 0; b < 4; ++b) {
        acc[a][b] = __builtin_amdgcn_mfma_f32_16x16x32_bf16(af[a], bff[b], acc[a][b], 0, 0, 0);
      }
    }
    __syncthreads();
  }
}

// ---------------- kernel 1: QKV projection -> Q,K (B,H,T,D) and V^T (B,H,D,T) ------
__global__ __launch_bounds__(256)
void k_gemm_qkv(const u16* __restrict__ xb, const u16* __restrict__ wb,
                const float* __restrict__ sq, const float* __restrict__ bq,
                const float* __restrict__ sk, const float* __restrict__ bk,
                const float* __restrict__ sv, const float* __restrict__ bv,
                u16* __restrict__ Qo, u16* __restrict__ Ko, u16* __restrict__ Vt) {
  __shared__ u16 As[128 * 32];
  __shared__ u16 Bs[128 * 32];
  const int bid  = blockIdx.x;
  const int brow = (bid & 31) * 128;
  const int ncol = (bid >> 5) * 128;   // 0..3071
  const int mat  = ncol >> 10;
  const int bcol = ncol & 1023;
  const u16* W = wb + (mat << 20);

  f32x4 acc[4][4];
  #pragma unroll
  for (int a = 0; a < 4; ++a)
    #pragma unroll
    for (int b = 0; b < 4; ++b) { f32x4 z = {0.f, 0.f, 0.f, 0.f}; acc[a][b] = z; }

  gemm_core(xb, W, brow, bcol, As, Bs, acc);

  const int tid = threadIdx.x;
  const int w = tid >> 6, lane = tid & 63;
  const int q = lane & 15, g = lane >> 4;
  const int wm = w >> 1, wn = w & 1;
  const float* sarr = (mat == 0) ? sq : (mat == 1) ? sk : sv;
  const float* barr = (mat == 0) ? bq : (mat == 1) ? bk : bv;

  #pragma unroll
  for (int bt = 0; bt < 4; ++bt) {
    const int c = bcol + wn * 64 + bt * 16 + q;   // channel within matrix, 0..1023
    const float sc = sarr[c];
    const float bi = barr[c];
    const int h = c >> 6, d = c & 63;
    #pragma unroll
    for (int a = 0; a < 4; ++a) {
      #pragma unroll
      for (int r = 0; r < 4; ++r) {
        const int m = brow + wm * 64 + a * 16 + 4 * g + r;  // token row 0..4095
        const int b_ = m >> 11, t = m & 2047;
        const u16 val = f2bf(acc[a][bt][r] * sc + bi);
        if (mat == 0)      Qo[(((size_t)(b_ * HH + h) * TT) + t) * DD + d] = val;
        else if (mat == 1) Ko[(((size_t)(b_ * HH + h) * TT) + t) * DD + d] = val;
        else               Vt[((size_t)(b_ * HH + h) * DD + d) * TT + t] = val;  // V^T direct
      }
    }
  }
}

// ---------------- kernel 2: causal flash attention, 32x32 MFMA ----------------------
// Block = 4 waves = 2 pairs; each pair processes 2 q-tiles (x, 63-x) sequentially so
// every block has identical work; grid 512 = exactly 2 blocks/CU, no tail.
// Pair's 2 waves stride alternate 64-key blocks (split-K online softmax), merged per
// tile via LDS. Swapped QK^T (S^T = K*Q^T, 32x32): lane owns q-row = lane&31; lane and
// lane+32 split the 64 keys -> single shfl_xor(32) max reduce, sum deferred to end.
// PV: O^T = V^T * P^T; P roundtrips via wave-private LDS (b128-aligned, stride 72).
__global__ __launch_bounds__(256, 3)
void k_attn(const u16* __restrict__ Q, const u16* __restrict__ K,
            const u16* __restrict__ Vt, u16* __restrict__ Y) {
  __shared__ u16 pbuf[4][32 * 72];     // per-wave P[q 0..31][key 0..63], stride 72
  __shared__ float mrg[2][64 * 36];    // per pair: lane slot = 32 O + m + l (stride 36)
  const int tid = threadIdx.x;
  const int w = tid >> 6, lane = tid & 63;
  const int q = lane & 31, hi = lane >> 5;
  const int p_ = w >> 1, u_ = w & 1;             // pair id, wave-in-pair
  const int bid = blockIdx.x;
  const int bh = bid & 31;                       // head-batch (low bits: XCD locality)
  const int grp = bid >> 5;                      // 0..15
  const int t0 = (p_ == 0) ? grp : (grp + 16);   // pair's first tile
  const u16* Qh = Q  + (size_t)bh * TT * DD;
  const u16* Kh = K  + (size_t)bh * TT * DD;
  const u16* Vh = Vt + (size_t)bh * DD * TT;
  u16* pl = pbuf[w];
  float* ms = &mrg[p_][lane * 36];
  const int b_ = bh >> 4, h = bh & 15;
  constexpr float SE = 0.125f * 1.44269504088896340736f;  // scale * log2(e)

  #pragma unroll
  for (int ti = 0; ti < 2; ++ti) {
    const int tile = (ti == 0) ? t0 : (63 - t0);
    const int qbase = tile * 32;
    const int qg = qbase + q;                    // this lane's q-row

    // Q fragments: B-operand, col=q, k(=d) = 16c + 8hi + e
    bf16x8 qf[4];
    #pragma unroll
    for (int c = 0; c < 4; ++c)
      qf[c] = *(const bf16x8*)&Qh[(qbase + q) * DD + 16 * c + 8 * hi];

    f32x16 oacc[2];                              // O^T[32d x 32q] per d-tile
    oacc[0] = f32x16{}; oacc[1] = f32x16{};
    float m_run = -__builtin_inff();
    float l_run = 0.f;
    const int nkb = (qbase + 95) >> 6;           // 64-key blocks covering 0..qbase+31

    for (int kb = u_; kb < nkb; kb += 2) {
      const int kbase = kb * 64;
      // K fragments: A-operand, row=key(lane&31), k(=d) = 16c + 8hi + e
      bf16x8 kf[2][4];
      #pragma unroll
      for (int s = 0; s < 2; ++s)
        #pragma unroll
        for (int c = 0; c < 4; ++c)
          kf[s][c] = *(const bf16x8*)&Kh[(kbase + 32 * s + q) * DD + 16 * c + 8 * hi];

      f32x16 sacc[2];
      sacc[0] = f32x16{}; sacc[1] = f32x16{};
      __builtin_amdgcn_s_setprio(1);
      #pragma unroll
      for (int c = 0; c < 4; ++c) {
        sacc[0] = __builtin_amdgcn_mfma_f32_32x32x16_bf16(kf[0][c], qf[c], sacc[0], 0, 0, 0);
        sacc[1] = __builtin_amdgcn_mfma_f32_32x32x16_bf16(kf[1][c], qf[c], sacc[1], 0, 0, 0);
      }
      __builtin_amdgcn_s_setprio(0);

      // V fragments for this block (latency hides under softmax):
      // A-operand, row = d_local(lane&31), k(=key) = 8hi + e within slice (s,c2)
      bf16x8 vf[2][2][2];
      #pragma unroll
      for (int dt = 0; dt < 2; ++dt)
        #pragma unroll
        for (int s = 0; s < 2; ++s)
          #pragma unroll
          for (int c2 = 0; c2 < 2; ++c2)
            vf[dt][s][c2] = *(const bf16x8*)
              &Vh[(dt * 32 + q) * TT + kbase + 32 * s + 16 * c2 + 8 * hi];

      // ---- softmax over this lane's 32 scores (keys (r&3)+8(r>>2)+4hi+32s) ----
      float sv[32];
      #pragma unroll
      for (int s = 0; s < 2; ++s)
        #pragma unroll
        for (int r = 0; r < 16; ++r) sv[s * 16 + r] = sacc[s][r] * SE;
      if (kbase + 63 > qbase) {                  // causal-partial block
        #pragma unroll
        for (int s = 0; s < 2; ++s)
          #pragma unroll
          for (int r = 0; r < 16; ++r)
            if (kbase + 32 * s + (r & 3) + 8 * (r >> 2) + 4 * hi > qg)
              sv[s * 16 + r] = -__builtin_inff();
      }
      float mx[16];
      #pragma unroll
      for (int u2 = 0; u2 < 16; ++u2) mx[u2] = fmaxf(sv[u2], sv[u2 + 16]);
      #pragma unroll
      for (int st = 8; st > 0; st >>= 1)
        #pragma unroll
        for (int u2 = 0; u2 < st; ++u2) mx[u2] = fmaxf(mx[u2], mx[u2 + st]);
      float pmax = fmaxf(mx[0], __shfl_xor(mx[0], 32));   // lane & lane+32 -> row max
      const bool keep = __all(pmax <= m_run + 8.0f);      // defer-max THR=8
      const float m_new = keep ? m_run : fmaxf(m_run, pmax);
      float p[32];
      #pragma unroll
      for (int u2 = 0; u2 < 32; ++u2) p[u2] = __builtin_amdgcn_exp2f(sv[u2] - m_new);
      float sm[16];
      #pragma unroll
      for (int u2 = 0; u2 < 16; ++u2) sm[u2] = p[u2] + p[u2 + 16];
      #pragma unroll
      for (int st = 8; st > 0; st >>= 1)
        #pragma unroll
        for (int u2 = 0; u2 < st; ++u2) sm[u2] += sm[u2 + st];
      if (keep) {
        l_run += sm[0];
      } else {
        const float alpha = __builtin_amdgcn_exp2f(m_run - m_new);
        l_run = l_run * alpha + sm[0];
        m_run = m_new;
        oacc[0] *= alpha;
        oacc[1] *= alpha;
      }

      // ---- pack P -> wave-private LDS (key-major per q-row) ----
      // p[s*16+r] is key 32s + (r&3)+8(r>>2)+4hi; r=4n..4n+3 -> keys 8n+4hi+0..3
      #pragma unroll
      for (int s = 0; s < 2; ++s)
        #pragma unroll
        for (int n = 0; n < 4; ++n) {
          u32 lo  = cvt_pk_bf16(p[s * 16 + 4 * n + 0], p[s * 16 + 4 * n + 1]);
          u32 hi2 = cvt_pk_bf16(p[s * 16 + 4 * n + 2], p[s * 16 + 4 * n + 3]);
          *(uint2*)&pl[q * 72 + 32 * s + 8 * n + 4 * hi] = make_uint2(lo, hi2);
        }

      // ---- PV: B-operand P^T[key][q]: col=q, k = 8hi + e within slice (s,c2) ----
      bf16x8 pf[2][2];
      #pragma unroll
      for (int s = 0; s < 2; ++s)
        #pragma unroll
        for (int c2 = 0; c2 < 2; ++c2)
          pf[s][c2] = *(const bf16x8*)&pl[q * 72 + 32 * s + 16 * c2 + 8 * hi];
      __builtin_amdgcn_s_setprio(1);
      #pragma unroll
      for (int s = 0; s < 2; ++s)
        #pragma unroll
        for (int c2 = 0; c2 < 2; ++c2) {
          oacc[0] = __builtin_amdgcn_mfma_f32_32x32x16_bf16(vf[0][s][c2], pf[s][c2], oacc[0], 0, 0, 0);
          oacc[1] = __builtin_amdgcn_mfma_f32_32x32x16_bf16(vf[1][s][c2], pf[s][c2], oacc[1], 0, 0, 0);
        }
      __builtin_amdgcn_s_setprio(0);
    }

    // ---- pair merge: u=1 publishes (O,m,l); u=0 combines + writes ----
    if (u_ == 1) {
      #pragma unroll
      for (int dt = 0; dt < 2; ++dt)
        #pragma unroll
        for (int e = 0; e < 16; ++e) ms[dt * 16 + e] = oacc[dt][e];
      ms[32] = m_run;
      ms[33] = l_run;
    }
    __syncthreads();
    if (u_ == 0) {
      const float m1 = ms[32], l1 = ms[33];
      const float mt = fmaxf(m_run, m1);
      const float s0 = __builtin_amdgcn_exp2f(m_run - mt);
      const float s1 = __builtin_amdgcn_exp2f(m1 - mt);    // m1=-inf -> 0
      float lt = l_run * s0 + l1 * s1;
      lt += __shfl_xor(lt, 32);                            // lane & lane+32 partials
      const float inv = 1.f / (lt + 1e-8f);
      #pragma unroll
      for (int dt = 0; dt < 2; ++dt)
        #pragma unroll
        for (int n = 0; n < 4; ++n) {
          const float o0 = (oacc[dt][4 * n + 0] * s0 + ms[dt * 16 + 4 * n + 0] * s1) * inv;
          const float o1 = (oacc[dt][4 * n + 1] * s0 + ms[dt * 16 + 4 * n + 1] * s1) * inv;
          const float o2 = (oacc[dt][4 * n + 2] * s0 + ms[dt * 16 + 4 * n + 2] * s1) * inv;
          const float o3 = (oacc[dt][4 * n + 3] * s0 + ms[dt * 16 + 4 * n + 3] * s1) * inv;
          u32 lo  = cvt_pk_bf16(o0, o1);
          u32 hi2 = cvt_pk_bf16(o2, o3);
          // d = 32dt + 8n + 4hi + {0..3}
          *(uint2*)&Y[(size_t)(b_ * TT + qg) * CC + h * 64 + 32 * dt + 8 * n + 4 * hi]
            = make_uint2(lo, hi2);
        }
    }
    __syncthreads();   // protect mrg before next tile's publish
  }
}

// ---------------- kernel 3: output projection -> fp32 d_out -------------------------
__global__ __launch_bounds__(256)
void k_gemm_o(const u16* __restrict__ Yb, const u16* __restrict__ Wo,
              const float* __restrict__ so, const float* __restrict__ bo,
              float* __restrict__ out) {
  __shared__ u16 As[128 * 32];
  __shared__ u16 Bs[128 * 32];
  const int bid = blockIdx.x;
  const int brow = (bid & 31) * 128;
  const int bcol = (bid >> 5) * 128;
  f32x4 acc[4][4];
  #pragma unroll
  for (int a = 0; a < 4; ++a)
    #pragma unroll
    for (int b = 0; b < 4; ++b) { f32x4 z = {0.f, 0.f, 0.f, 0.f}; acc[a][b] = z; }

  gemm_core(Yb, Wo, brow, bcol, As, Bs, acc);

  const int tid = threadIdx.x;
  const int w = tid >> 6, lane = tid & 63;
  const int q = lane & 15, g = lane >> 4;
  const int wm = w >> 1, wn = w & 1;
  #pragma unroll
  for (int bt = 0; bt < 4; ++bt) {
    const int c = bcol + wn * 64 + bt * 16 + q;
    const float sc = so[c], bi = bo[c];
    #pragma unroll
    for (int a = 0; a < 4; ++a) {
      const int mbase = brow + wm * 64 + a * 16 + 4 * g;
      #pragma unroll
      for (int r = 0; r < 4; ++r) {
        out[(size_t)(mbase + r) * CC + c] = acc[a][bt][r] * sc + bi;
      }
    }
  }
}

// ---------------- launcher -----------------------------------------------------------
extern "C" void kernel_launch(void* const* d_in, const int* in_sizes, int n_in,
                              void* d_out, int out_size, void* d_ws, size_t ws_size,
                              hipStream_t stream) {
  const float* x  = (const float*)d_in[0];
  const int*   wq = (const int*)d_in[1];
  const float* sq = (const float*)d_in[2];
  const float* bq = (const float*)d_in[3];
  const int*   wk = (const int*)d_in[4];
  const float* sk = (const float*)d_in[5];
  const float* bk = (const float*)d_in[6];
  const int*   wv = (const int*)d_in[7];
  const float* sv = (const float*)d_in[8];
  const float* bv = (const float*)d_in[9];
  const int*   wo = (const int*)d_in[10];
  const float* so = (const float*)d_in[11];
  const float* bo = (const float*)d_in[12];

  const size_t NEED = (40u << 20);
  if (ws_size < NEED) {   // diagnostic: error magnitude ~9999 => scratch too small
    k_sentinel<<<dim3((out_size + 255) / 256), dim3(256), 0, stream>>>((float*)d_out, out_size);
    return;
  }

  char* ws = (char*)d_ws;
  u16* xb = (u16*)(ws);                      // 8 MB  (x bf16; reused as Y later)
  u16* wb = (u16*)(ws + (8u  << 20));        // 8 MB  (4 weight matrices bf16)
  u16* Qb = (u16*)(ws + (16u << 20));        // 8 MB
  u16* Kb = (u16*)(ws + (24u << 20));        // 8 MB
  u16* Vt = (u16*)(ws + (32u << 20));        // 8 MB  (V^T, written directly by QKV GEMM)
  u16* Yb = xb;                              // x dead after QKV GEMM

  k_convert <<<dim3(8192), dim3(256), 0, stream>>>(x, wq, wk, wv, wo, xb, wb);
  k_gemm_qkv<<<dim3(768),  dim3(256), 0, stream>>>(xb, wb, sq, bq, sk, bk, sv, bv, Qb, Kb, Vt);
  k_attn    <<<dim3(512),  dim3(256), 0, stream>>>(Qb, Kb, Vt, Yb);
  k_gemm_o  <<<dim3(256),  dim3(256), 0, stream>>>(Yb, wb + (3u << 20), so, bo, (float*)d_out);
}